// Round 1
// baseline (2995.093 us; speedup 1.0000x reference)
//
#include <hip/hip_runtime.h>
#include <cstddef>
#include <cstdint>

#define F 128
#define C_OUT 10

// ---------------- GRU weight evolution: W' = GRU(W0, W0) ----------------
__global__ void gru_evolve_k(const float* __restrict__ W0,
                             const float* __restrict__ wih,
                             const float* __restrict__ whh,
                             const float* __restrict__ bih,
                             const float* __restrict__ bhh,
                             float* __restrict__ Wout) {
  int t = blockIdx.x * blockDim.x + threadIdx.x;   // 0..16383
  int i = t >> 7, j = t & 127;
  const float4* w0r = (const float4*)(W0 + (size_t)i * F);
  float gi[3], gh[3];
#pragma unroll
  for (int g = 0; g < 3; ++g) {
    const float4* wr = (const float4*)(wih + (size_t)(g * F + j) * F);
    const float4* hr = (const float4*)(whh + (size_t)(g * F + j) * F);
    float si = 0.f, sh = 0.f;
    for (int k = 0; k < F / 4; ++k) {
      float4 a = w0r[k];
      float4 b = wr[k];
      float4 c = hr[k];
      si += a.x * b.x + a.y * b.y + a.z * b.z + a.w * b.w;
      sh += a.x * c.x + a.y * c.y + a.z * c.z + a.w * c.w;
    }
    gi[g] = si + bih[g * F + j];
    gh[g] = sh + bhh[g * F + j];
  }
  float r = 1.0f / (1.0f + expf(-(gi[0] + gh[0])));
  float z = 1.0f / (1.0f + expf(-(gi[1] + gh[1])));
  float n = tanhf(gi[2] + r * gh[2]);
  Wout[(size_t)i * F + j] = (1.0f - z) * n + z * W0[(size_t)i * F + j];
}

// ---------------- degree / normalization ----------------
__global__ void deg_k(const int* __restrict__ dst, float* __restrict__ deg, int E) {
  int e = blockIdx.x * blockDim.x + threadIdx.x;
  if (e < E) atomicAdd(&deg[dst[e]], 1.0f);
}

__global__ void dinv_k(float* __restrict__ deg, int n) {
  int i = blockIdx.x * blockDim.x + threadIdx.x;
  if (i < n) deg[i] = rsqrtf(deg[i] + 1.0f);   // +1 = self loop; always > 0
}

// ---------------- Y = X @ W  (X: nrows x 128, W: 128 x 128) ----------------
// One wave = 64 rows, one 32-col chunk. W addresses are wave-uniform -> s_load.
__global__ void gemm128_k(const float* __restrict__ X, const float* __restrict__ W,
                          float* __restrict__ Y, int nrows) {
  int lane = threadIdx.x & 63;
  int j0 = __builtin_amdgcn_readfirstlane((int)(threadIdx.x >> 6) * 32);
  int row = blockIdx.x * 64 + lane;
  if (row >= nrows) return;
  float4 acc[8];
#pragma unroll
  for (int jj = 0; jj < 8; ++jj) acc[jj] = make_float4(0.f, 0.f, 0.f, 0.f);
  const float* xr = X + (size_t)row * F;
  for (int k = 0; k < F; k += 4) {
    float4 xk = *(const float4*)(xr + k);
#pragma unroll
    for (int kk = 0; kk < 4; ++kk) {
      float xv = (kk == 0) ? xk.x : (kk == 1) ? xk.y : (kk == 2) ? xk.z : xk.w;
      const float4* wr = (const float4*)(W + (size_t)(k + kk) * F + j0);
#pragma unroll
      for (int jj = 0; jj < 8; ++jj) {
        float4 w4 = wr[jj];
        acc[jj].x = fmaf(xv, w4.x, acc[jj].x);
        acc[jj].y = fmaf(xv, w4.y, acc[jj].y);
        acc[jj].z = fmaf(xv, w4.z, acc[jj].z);
        acc[jj].w = fmaf(xv, w4.w, acc[jj].w);
      }
    }
  }
  float4* yr = (float4*)(Y + (size_t)row * F + j0);
#pragma unroll
  for (int jj = 0; jj < 8; ++jj) yr[jj] = acc[jj];
}

// ---------------- edge aggregation: out[dst] += dinv[s]*dinv[d] * xw[src] ----------------
__global__ void agg_k(const int* __restrict__ src, const int* __restrict__ dst,
                      const float* __restrict__ dinv, const float* __restrict__ xw,
                      float* __restrict__ outp, int E) {
  int idx = blockIdx.x * blockDim.x + threadIdx.x;   // E*32 = 25.6M < 2^31
  if (idx >= E * 32) return;
  int e = idx >> 5;
  int c = (idx & 31) << 2;
  int s = src[e], d = dst[e];
  float nr = dinv[s] * dinv[d];
  float4 v = *(const float4*)(xw + (size_t)s * F + c);
  float* o = outp + (size_t)d * F + c;
  atomicAdd(o + 0, nr * v.x);
  atomicAdd(o + 1, nr * v.y);
  atomicAdd(o + 2, nr * v.z);
  atomicAdd(o + 3, nr * v.w);
}

// ---------------- self-loop + relu: h = relu(agg + dinv^2 * xw) ----------------
__global__ void finish_relu_k(float* __restrict__ agg, const float* __restrict__ xw,
                              const float* __restrict__ dinv, int n) {
  int idx = blockIdx.x * blockDim.x + threadIdx.x;
  if (idx >= n * 32) return;
  int i = idx >> 5;
  int c = (idx & 31) << 2;
  float di = dinv[i];
  float sc = di * di;
  float4 a = *(float4*)(agg + (size_t)i * F + c);
  float4 x = *(const float4*)(xw + (size_t)i * F + c);
  float4 r;
  r.x = fmaxf(fmaf(sc, x.x, a.x), 0.f);
  r.y = fmaxf(fmaf(sc, x.y, a.y), 0.f);
  r.z = fmaxf(fmaf(sc, x.z, a.z), 0.f);
  r.w = fmaxf(fmaf(sc, x.w, a.w), 0.f);
  *(float4*)(agg + (size_t)i * F + c) = r;
}

// ---------------- logits + log_softmax ----------------
__global__ void logits_k(const float* __restrict__ h, const float* __restrict__ lw,
                         const float* __restrict__ lb, float* __restrict__ out, int n) {
  int i = blockIdx.x * blockDim.x + threadIdx.x;
  if (i >= n) return;
  float acc[C_OUT];
#pragma unroll
  for (int c = 0; c < C_OUT; ++c) acc[c] = lb[c];
  const float4* hr = (const float4*)(h + (size_t)i * F);
  for (int k = 0; k < F / 4; ++k) {
    float4 hv = hr[k];
#pragma unroll
    for (int c = 0; c < C_OUT; ++c) {
      float4 w = *(const float4*)(lw + (size_t)c * F + k * 4);
      acc[c] += hv.x * w.x + hv.y * w.y + hv.z * w.z + hv.w * w.w;
    }
  }
  float m = acc[0];
#pragma unroll
  for (int c = 1; c < C_OUT; ++c) m = fmaxf(m, acc[c]);
  float s = 0.f;
#pragma unroll
  for (int c = 0; c < C_OUT; ++c) s += expf(acc[c] - m);
  float lse = m + logf(s);
#pragma unroll
  for (int c = 0; c < C_OUT; ++c) out[(size_t)i * C_OUT + c] = acc[c] - lse;
}

extern "C" void kernel_launch(void* const* d_in, const int* in_sizes, int n_in,
                              void* d_out, int out_size, void* d_ws, size_t ws_size,
                              hipStream_t stream) {
  const float* x    = (const float*)d_in[0];
  const int*   ei   = (const int*)d_in[1];
  const float* W1   = (const float*)d_in[2];
  const float* wih1 = (const float*)d_in[3];
  const float* whh1 = (const float*)d_in[4];
  const float* bih1 = (const float*)d_in[5];
  const float* bhh1 = (const float*)d_in[6];
  const float* W2   = (const float*)d_in[7];
  const float* wih2 = (const float*)d_in[8];
  const float* whh2 = (const float*)d_in[9];
  const float* bih2 = (const float*)d_in[10];
  const float* bhh2 = (const float*)d_in[11];
  const float* lw   = (const float*)d_in[12];
  const float* lb   = (const float*)d_in[13];
  float* out = (float*)d_out;

  int N = in_sizes[0] / F;
  int E = in_sizes[1] / 2;
  const int* src = ei;
  const int* dst = ei + E;

  float* ws   = (float*)d_ws;
  float* bufA = ws;                        // N*F  (xw)
  float* bufB = bufA + (size_t)N * F;      // N*F  (agg / h)
  float* dinv = bufB + (size_t)N * F;      // N
  float* W1e  = dinv + N;                  // F*F
  float* W2e  = W1e + F * F;               // F*F

  // evolve weights (tiny)
  gru_evolve_k<<<(F * F) / 256, 256, 0, stream>>>(W1, wih1, whh1, bih1, bhh1, W1e);
  gru_evolve_k<<<(F * F) / 256, 256, 0, stream>>>(W2, wih2, whh2, bih2, bhh2, W2e);

  // normalization
  hipMemsetAsync(dinv, 0, (size_t)N * sizeof(float), stream);
  deg_k<<<(E + 255) / 256, 256, 0, stream>>>(dst, dinv, E);
  dinv_k<<<(N + 255) / 256, 256, 0, stream>>>(dinv, N);

  // ----- layer 1 -----
  gemm128_k<<<(N + 63) / 64, 256, 0, stream>>>(x, W1e, bufA, N);
  hipMemsetAsync(bufB, 0, (size_t)N * F * sizeof(float), stream);
  agg_k<<<(E * 32 + 255) / 256, 256, 0, stream>>>(src, dst, dinv, bufA, bufB, E);
  finish_relu_k<<<(N * 32 + 255) / 256, 256, 0, stream>>>(bufB, bufA, dinv, N);

  // ----- layer 2 -----
  gemm128_k<<<(N + 63) / 64, 256, 0, stream>>>(bufB, W2e, bufA, N);
  hipMemsetAsync(bufB, 0, (size_t)N * F * sizeof(float), stream);
  agg_k<<<(E * 32 + 255) / 256, 256, 0, stream>>>(src, dst, dinv, bufA, bufB, E);
  finish_relu_k<<<(N * 32 + 255) / 256, 256, 0, stream>>>(bufB, bufA, dinv, N);

  // ----- classifier -----
  logits_k<<<(N + 255) / 256, 256, 0, stream>>>(bufB, lw, lb, out, N);
}

// Round 2
// 706.725 us; speedup vs baseline: 4.2380x; 4.2380x over previous
//
#include <hip/hip_runtime.h>
#include <cstddef>
#include <cstdint>

#define F 128
#define C_OUT 10

// ---------------- GRU weight evolution: W' = GRU(W0, W0) ----------------
__global__ void gru_evolve_k(const float* __restrict__ W0,
                             const float* __restrict__ wih,
                             const float* __restrict__ whh,
                             const float* __restrict__ bih,
                             const float* __restrict__ bhh,
                             float* __restrict__ Wout) {
  int t = blockIdx.x * blockDim.x + threadIdx.x;   // 0..16383
  int i = t >> 7, j = t & 127;
  const float4* w0r = (const float4*)(W0 + (size_t)i * F);
  float gi[3], gh[3];
#pragma unroll
  for (int g = 0; g < 3; ++g) {
    const float4* wr = (const float4*)(wih + (size_t)(g * F + j) * F);
    const float4* hr = (const float4*)(whh + (size_t)(g * F + j) * F);
    float si = 0.f, sh = 0.f;
    for (int k = 0; k < F / 4; ++k) {
      float4 a = w0r[k];
      float4 b = wr[k];
      float4 c = hr[k];
      si += a.x * b.x + a.y * b.y + a.z * b.z + a.w * b.w;
      sh += a.x * c.x + a.y * c.y + a.z * c.z + a.w * c.w;
    }
    gi[g] = si + bih[g * F + j];
    gh[g] = sh + bhh[g * F + j];
  }
  float r = 1.0f / (1.0f + expf(-(gi[0] + gh[0])));
  float z = 1.0f / (1.0f + expf(-(gi[1] + gh[1])));
  float n = tanhf(gi[2] + r * gh[2]);
  Wout[(size_t)i * F + j] = (1.0f - z) * n + z * W0[(size_t)i * F + j];
}

// ---------------- CSR build ----------------
__global__ void count_k(const int* __restrict__ dst, int* __restrict__ counts, int E) {
  int e = blockIdx.x * blockDim.x + threadIdx.x;
  if (e < E) atomicAdd(&counts[dst[e]], 1);
}

// single block, 1024 threads: exclusive scan counts -> rowptr, plus dinv = rsqrt(deg+1)
__global__ void scan_k(const int* __restrict__ counts, int* __restrict__ rowptr,
                       float* __restrict__ dinv, int n) {
  __shared__ int partial[1024];
  int tid = threadIdx.x;
  int per = (n + 1023) / 1024;
  int start = tid * per;
  int end = start + per; if (end > n) end = n;
  int s = 0;
  for (int i = start; i < end; ++i) s += counts[i];
  partial[tid] = s;
  __syncthreads();
  for (int off = 1; off < 1024; off <<= 1) {
    int v = 0;
    if (tid >= off) v = partial[tid - off];
    __syncthreads();
    if (tid >= off) partial[tid] += v;
    __syncthreads();
  }
  int base = (tid == 0) ? 0 : partial[tid - 1];
  for (int i = start; i < end; ++i) {
    rowptr[i] = base;
    int c = counts[i];
    base += c;
    dinv[i] = rsqrtf((float)c + 1.0f);
  }
  if (tid == 1023) rowptr[n] = base;
}

__global__ void fill_k(const int* __restrict__ src, const int* __restrict__ dst,
                       int* __restrict__ cursor, int* __restrict__ csr_src, int E) {
  int e = blockIdx.x * blockDim.x + threadIdx.x;
  if (e < E) {
    int d = dst[e];
    int pos = atomicAdd(&cursor[d], 1);
    csr_src[pos] = src[e];
  }
}

// ---------------- Y = X @ W  (X: nrows x 128, W: 128 x 128) ----------------
__global__ void gemm128_k(const float* __restrict__ X, const float* __restrict__ W,
                          float* __restrict__ Y, int nrows) {
  int lane = threadIdx.x & 63;
  int j0 = __builtin_amdgcn_readfirstlane((int)(threadIdx.x >> 6) * 32);
  int row = blockIdx.x * 64 + lane;
  if (row >= nrows) return;
  float4 acc[8];
#pragma unroll
  for (int jj = 0; jj < 8; ++jj) acc[jj] = make_float4(0.f, 0.f, 0.f, 0.f);
  const float* xr = X + (size_t)row * F;
  for (int k = 0; k < F; k += 4) {
    float4 xk = *(const float4*)(xr + k);
#pragma unroll
    for (int kk = 0; kk < 4; ++kk) {
      float xv = (kk == 0) ? xk.x : (kk == 1) ? xk.y : (kk == 2) ? xk.z : xk.w;
      const float4* wr = (const float4*)(W + (size_t)(k + kk) * F + j0);
#pragma unroll
      for (int jj = 0; jj < 8; ++jj) {
        float4 w4 = wr[jj];
        acc[jj].x = fmaf(xv, w4.x, acc[jj].x);
        acc[jj].y = fmaf(xv, w4.y, acc[jj].y);
        acc[jj].z = fmaf(xv, w4.z, acc[jj].z);
        acc[jj].w = fmaf(xv, w4.w, acc[jj].w);
      }
    }
  }
  float4* yr = (float4*)(Y + (size_t)row * F + j0);
#pragma unroll
  for (int jj = 0; jj < 8; ++jj) yr[jj] = acc[jj];
}

// ---------------- gather aggregation + self-loop + relu ----------------
// 2 nodes per 256-thread block; 128 threads (2 waves) per node, one column each.
__global__ void agg_gather_k(const int* __restrict__ rowptr, const int* __restrict__ csr_src,
                             const float* __restrict__ dinv, const float* __restrict__ xw,
                             float* __restrict__ outp, int n) {
  int node = blockIdx.x * 2 + (threadIdx.x >> 7);
  if (node >= n) return;
  int col = threadIdx.x & 127;
  float dd = dinv[node];
  float acc = dd * dd * xw[(size_t)node * F + col];   // self loop
  int b = rowptr[node], e = rowptr[node + 1];
  for (int i = b; i < e; ++i) {
    int s = csr_src[i];
    float nr = dd * dinv[s];
    acc = fmaf(nr, xw[(size_t)s * F + col], acc);
  }
  outp[(size_t)node * F + col] = fmaxf(acc, 0.f);
}

// ---------------- logits + log_softmax ----------------
__global__ void logits_k(const float* __restrict__ h, const float* __restrict__ lw,
                         const float* __restrict__ lb, float* __restrict__ out, int n) {
  int i = blockIdx.x * blockDim.x + threadIdx.x;
  if (i >= n) return;
  float acc[C_OUT];
#pragma unroll
  for (int c = 0; c < C_OUT; ++c) acc[c] = lb[c];
  const float4* hr = (const float4*)(h + (size_t)i * F);
  for (int k = 0; k < F / 4; ++k) {
    float4 hv = hr[k];
#pragma unroll
    for (int c = 0; c < C_OUT; ++c) {
      float4 w = *(const float4*)(lw + (size_t)c * F + k * 4);
      acc[c] += hv.x * w.x + hv.y * w.y + hv.z * w.z + hv.w * w.w;
    }
  }
  float m = acc[0];
#pragma unroll
  for (int c = 1; c < C_OUT; ++c) m = fmaxf(m, acc[c]);
  float s = 0.f;
#pragma unroll
  for (int c = 0; c < C_OUT; ++c) s += expf(acc[c] - m);
  float lse = m + logf(s);
#pragma unroll
  for (int c = 0; c < C_OUT; ++c) out[(size_t)i * C_OUT + c] = acc[c] - lse;
}

extern "C" void kernel_launch(void* const* d_in, const int* in_sizes, int n_in,
                              void* d_out, int out_size, void* d_ws, size_t ws_size,
                              hipStream_t stream) {
  const float* x    = (const float*)d_in[0];
  const int*   ei   = (const int*)d_in[1];
  const float* W1   = (const float*)d_in[2];
  const float* wih1 = (const float*)d_in[3];
  const float* whh1 = (const float*)d_in[4];
  const float* bih1 = (const float*)d_in[5];
  const float* bhh1 = (const float*)d_in[6];
  const float* W2   = (const float*)d_in[7];
  const float* wih2 = (const float*)d_in[8];
  const float* whh2 = (const float*)d_in[9];
  const float* bih2 = (const float*)d_in[10];
  const float* bhh2 = (const float*)d_in[11];
  const float* lw   = (const float*)d_in[12];
  const float* lb   = (const float*)d_in[13];
  float* out = (float*)d_out;

  int N = in_sizes[0] / F;
  int E = in_sizes[1] / 2;
  const int* src = ei;
  const int* dst = ei + E;

  float* ws   = (float*)d_ws;
  float* bufA = ws;                        // N*F  (xw)
  float* bufB = bufA + (size_t)N * F;      // N*F  (h)
  float* dinv = bufB + (size_t)N * F;      // N
  float* W1e  = dinv + N;                  // F*F
  float* W2e  = W1e + F * F;               // F*F
  int* counts = (int*)(W2e + F * F);       // N
  int* rowptr = counts + N;                // N+1
  int* cursor = rowptr + N + 1;            // N
  int* csr_src = cursor + N;               // E

  // evolve weights (tiny)
  gru_evolve_k<<<(F * F) / 256, 256, 0, stream>>>(W1, wih1, whh1, bih1, bhh1, W1e);
  gru_evolve_k<<<(F * F) / 256, 256, 0, stream>>>(W2, wih2, whh2, bih2, bhh2, W2e);

  // ----- CSR build + normalization -----
  hipMemsetAsync(counts, 0, (size_t)N * sizeof(int), stream);
  count_k<<<(E + 255) / 256, 256, 0, stream>>>(dst, counts, E);
  scan_k<<<1, 1024, 0, stream>>>(counts, rowptr, dinv, N);
  hipMemcpyAsync(cursor, rowptr, (size_t)N * sizeof(int), hipMemcpyDeviceToDevice, stream);
  fill_k<<<(E + 255) / 256, 256, 0, stream>>>(src, dst, cursor, csr_src, E);

  // ----- layer 1 -----
  gemm128_k<<<(N + 63) / 64, 256, 0, stream>>>(x, W1e, bufA, N);
  agg_gather_k<<<(N + 1) / 2, 256, 0, stream>>>(rowptr, csr_src, dinv, bufA, bufB, N);

  // ----- layer 2 -----
  gemm128_k<<<(N + 63) / 64, 256, 0, stream>>>(bufB, W2e, bufA, N);
  agg_gather_k<<<(N + 1) / 2, 256, 0, stream>>>(rowptr, csr_src, dinv, bufA, bufB, N);

  // ----- classifier -----
  logits_k<<<(N + 255) / 256, 256, 0, stream>>>(bufB, lw, lb, out, N);
}

// Round 3
// 541.668 us; speedup vs baseline: 5.5294x; 1.3047x over previous
//
#include <hip/hip_runtime.h>
#include <cstddef>
#include <cstdint>

#define F 128
#define C_OUT 10

// ---------------- GRU weight evolution: W' = GRU(W0, W0) ----------------
__global__ void gru_evolve_k(const float* __restrict__ W0,
                             const float* __restrict__ wih,
                             const float* __restrict__ whh,
                             const float* __restrict__ bih,
                             const float* __restrict__ bhh,
                             float* __restrict__ Wout) {
  int t = blockIdx.x * blockDim.x + threadIdx.x;   // 0..16383
  int i = t >> 7, j = t & 127;
  const float4* w0r = (const float4*)(W0 + (size_t)i * F);
  float gi[3], gh[3];
#pragma unroll
  for (int g = 0; g < 3; ++g) {
    const float4* wr = (const float4*)(wih + (size_t)(g * F + j) * F);
    const float4* hr = (const float4*)(whh + (size_t)(g * F + j) * F);
    float si = 0.f, sh = 0.f;
    for (int k = 0; k < F / 4; ++k) {
      float4 a = w0r[k];
      float4 b = wr[k];
      float4 c = hr[k];
      si += a.x * b.x + a.y * b.y + a.z * b.z + a.w * b.w;
      sh += a.x * c.x + a.y * c.y + a.z * c.z + a.w * c.w;
    }
    gi[g] = si + bih[g * F + j];
    gh[g] = sh + bhh[g * F + j];
  }
  float r = 1.0f / (1.0f + expf(-(gi[0] + gh[0])));
  float z = 1.0f / (1.0f + expf(-(gi[1] + gh[1])));
  float n = tanhf(gi[2] + r * gh[2]);
  Wout[(size_t)i * F + j] = (1.0f - z) * n + z * W0[(size_t)i * F + j];
}

// ---------------- CSR build ----------------
__global__ void count_k(const int* __restrict__ dst, int* __restrict__ counts, int E) {
  int e = blockIdx.x * blockDim.x + threadIdx.x;
  if (e < E) atomicAdd(&counts[dst[e]], 1);
}

// single block, 1024 threads: exclusive scan counts -> rowptr, plus dinv = rsqrt(deg+1)
__global__ void scan_k(const int* __restrict__ counts, int* __restrict__ rowptr,
                       float* __restrict__ dinv, int n) {
  __shared__ int partial[1024];
  int tid = threadIdx.x;
  int per = (n + 1023) / 1024;
  int start = tid * per;
  int end = start + per; if (end > n) end = n;
  int s = 0;
  for (int i = start; i < end; ++i) s += counts[i];
  partial[tid] = s;
  __syncthreads();
  for (int off = 1; off < 1024; off <<= 1) {
    int v = 0;
    if (tid >= off) v = partial[tid - off];
    __syncthreads();
    if (tid >= off) partial[tid] += v;
    __syncthreads();
  }
  int base = (tid == 0) ? 0 : partial[tid - 1];
  for (int i = start; i < end; ++i) {
    rowptr[i] = base;
    int c = counts[i];
    base += c;
    dinv[i] = rsqrtf((float)c + 1.0f);
  }
  if (tid == 1023) rowptr[n] = base;
}

__global__ void fill_k(const int* __restrict__ src, const int* __restrict__ dst,
                       int* __restrict__ cursor, int* __restrict__ csr_src, int E) {
  int e = blockIdx.x * blockDim.x + threadIdx.x;
  if (e < E) {
    int d = dst[e];
    int pos = atomicAdd(&cursor[d], 1);
    csr_src[pos] = src[e];
  }
}

// ---------------- Y = X @ W  (X: nrows x 128, W: 128 x 128) ----------------
__global__ void gemm128_k(const float* __restrict__ X, const float* __restrict__ W,
                          float* __restrict__ Y, int nrows) {
  int lane = threadIdx.x & 63;
  int j0 = __builtin_amdgcn_readfirstlane((int)(threadIdx.x >> 6) * 32);
  int row = blockIdx.x * 64 + lane;
  if (row >= nrows) return;
  float4 acc[8];
#pragma unroll
  for (int jj = 0; jj < 8; ++jj) acc[jj] = make_float4(0.f, 0.f, 0.f, 0.f);
  const float* xr = X + (size_t)row * F;
  for (int k = 0; k < F; k += 4) {
    float4 xk = *(const float4*)(xr + k);
#pragma unroll
    for (int kk = 0; kk < 4; ++kk) {
      float xv = (kk == 0) ? xk.x : (kk == 1) ? xk.y : (kk == 2) ? xk.z : xk.w;
      const float4* wr = (const float4*)(W + (size_t)(k + kk) * F + j0);
#pragma unroll
      for (int jj = 0; jj < 8; ++jj) {
        float4 w4 = wr[jj];
        acc[jj].x = fmaf(xv, w4.x, acc[jj].x);
        acc[jj].y = fmaf(xv, w4.y, acc[jj].y);
        acc[jj].z = fmaf(xv, w4.z, acc[jj].z);
        acc[jj].w = fmaf(xv, w4.w, acc[jj].w);
      }
    }
  }
  float4* yr = (float4*)(Y + (size_t)row * F + j0);
#pragma unroll
  for (int jj = 0; jj < 8; ++jj) yr[jj] = acc[jj];
}

// ---------------- gather aggregation + self-loop + relu ----------------
// One wave (64 lanes) per node; each lane owns a float2 column pair.
// Node-uniform values forced scalar via readfirstlane -> s_load for csr/dinv.
// 8-wide unrolled edge loop => 8 outstanding 512B row loads per wave.
__global__ void agg_gather_k(const int* __restrict__ rowptr, const int* __restrict__ csr_src,
                             const float* __restrict__ dinv, const float* __restrict__ xw,
                             float* __restrict__ outp, int n) {
  int wave = (int)((blockIdx.x * blockDim.x + threadIdx.x) >> 6);
  int lane = threadIdx.x & 63;
  if (wave >= n) return;
  int node = __builtin_amdgcn_readfirstlane(wave);
  const float2* __restrict__ xw2 = (const float2*)xw;
  float dd = dinv[node];
  float2 me = xw2[(size_t)node * 64 + lane];
  float accx = dd * dd * me.x;
  float accy = dd * dd * me.y;
  int b = rowptr[node], e = rowptr[node + 1];
  int i = b;
  for (; i + 8 <= e; i += 8) {
    int s0 = csr_src[i + 0], s1 = csr_src[i + 1], s2 = csr_src[i + 2], s3 = csr_src[i + 3];
    int s4 = csr_src[i + 4], s5 = csr_src[i + 5], s6 = csr_src[i + 6], s7 = csr_src[i + 7];
    float w0 = dinv[s0], w1 = dinv[s1], w2 = dinv[s2], w3 = dinv[s3];
    float w4 = dinv[s4], w5 = dinv[s5], w6 = dinv[s6], w7 = dinv[s7];
    float2 v0 = xw2[(size_t)s0 * 64 + lane];
    float2 v1 = xw2[(size_t)s1 * 64 + lane];
    float2 v2 = xw2[(size_t)s2 * 64 + lane];
    float2 v3 = xw2[(size_t)s3 * 64 + lane];
    float2 v4 = xw2[(size_t)s4 * 64 + lane];
    float2 v5 = xw2[(size_t)s5 * 64 + lane];
    float2 v6 = xw2[(size_t)s6 * 64 + lane];
    float2 v7 = xw2[(size_t)s7 * 64 + lane];
    accx = fmaf(dd * w0, v0.x, accx); accy = fmaf(dd * w0, v0.y, accy);
    accx = fmaf(dd * w1, v1.x, accx); accy = fmaf(dd * w1, v1.y, accy);
    accx = fmaf(dd * w2, v2.x, accx); accy = fmaf(dd * w2, v2.y, accy);
    accx = fmaf(dd * w3, v3.x, accx); accy = fmaf(dd * w3, v3.y, accy);
    accx = fmaf(dd * w4, v4.x, accx); accy = fmaf(dd * w4, v4.y, accy);
    accx = fmaf(dd * w5, v5.x, accx); accy = fmaf(dd * w5, v5.y, accy);
    accx = fmaf(dd * w6, v6.x, accx); accy = fmaf(dd * w6, v6.y, accy);
    accx = fmaf(dd * w7, v7.x, accx); accy = fmaf(dd * w7, v7.y, accy);
  }
  for (; i < e; ++i) {
    int s = csr_src[i];
    float w = dinv[s];
    float2 v = xw2[(size_t)s * 64 + lane];
    accx = fmaf(dd * w, v.x, accx);
    accy = fmaf(dd * w, v.y, accy);
  }
  float2 r;
  r.x = fmaxf(accx, 0.f);
  r.y = fmaxf(accy, 0.f);
  ((float2*)outp)[(size_t)node * 64 + lane] = r;
}

// ---------------- logits + log_softmax ----------------
__global__ void logits_k(const float* __restrict__ h, const float* __restrict__ lw,
                         const float* __restrict__ lb, float* __restrict__ out, int n) {
  int i = blockIdx.x * blockDim.x + threadIdx.x;
  if (i >= n) return;
  float acc[C_OUT];
#pragma unroll
  for (int c = 0; c < C_OUT; ++c) acc[c] = lb[c];
  const float4* hr = (const float4*)(h + (size_t)i * F);
  for (int k = 0; k < F / 4; ++k) {
    float4 hv = hr[k];
#pragma unroll
    for (int c = 0; c < C_OUT; ++c) {
      float4 w = *(const float4*)(lw + (size_t)c * F + k * 4);
      acc[c] += hv.x * w.x + hv.y * w.y + hv.z * w.z + hv.w * w.w;
    }
  }
  float m = acc[0];
#pragma unroll
  for (int c = 1; c < C_OUT; ++c) m = fmaxf(m, acc[c]);
  float s = 0.f;
#pragma unroll
  for (int c = 0; c < C_OUT; ++c) s += expf(acc[c] - m);
  float lse = m + logf(s);
#pragma unroll
  for (int c = 0; c < C_OUT; ++c) out[(size_t)i * C_OUT + c] = acc[c] - lse;
}

extern "C" void kernel_launch(void* const* d_in, const int* in_sizes, int n_in,
                              void* d_out, int out_size, void* d_ws, size_t ws_size,
                              hipStream_t stream) {
  const float* x    = (const float*)d_in[0];
  const int*   ei   = (const int*)d_in[1];
  const float* W1   = (const float*)d_in[2];
  const float* wih1 = (const float*)d_in[3];
  const float* whh1 = (const float*)d_in[4];
  const float* bih1 = (const float*)d_in[5];
  const float* bhh1 = (const float*)d_in[6];
  const float* W2   = (const float*)d_in[7];
  const float* wih2 = (const float*)d_in[8];
  const float* whh2 = (const float*)d_in[9];
  const float* bih2 = (const float*)d_in[10];
  const float* bhh2 = (const float*)d_in[11];
  const float* lw   = (const float*)d_in[12];
  const float* lb   = (const float*)d_in[13];
  float* out = (float*)d_out;

  int N = in_sizes[0] / F;
  int E = in_sizes[1] / 2;
  const int* src = ei;
  const int* dst = ei + E;

  float* ws   = (float*)d_ws;
  float* bufA = ws;                        // N*F  (xw)
  float* bufB = bufA + (size_t)N * F;      // N*F  (h)
  float* dinv = bufB + (size_t)N * F;      // N
  float* W1e  = dinv + N;                  // F*F
  float* W2e  = W1e + F * F;               // F*F
  int* counts = (int*)(W2e + F * F);       // N
  int* rowptr = counts + N;                // N+1
  int* cursor = rowptr + N + 1;            // N
  int* csr_src = cursor + N;               // E

  // evolve weights (tiny)
  gru_evolve_k<<<(F * F) / 256, 256, 0, stream>>>(W1, wih1, whh1, bih1, bhh1, W1e);
  gru_evolve_k<<<(F * F) / 256, 256, 0, stream>>>(W2, wih2, whh2, bih2, bhh2, W2e);

  // ----- CSR build + normalization -----
  hipMemsetAsync(counts, 0, (size_t)N * sizeof(int), stream);
  count_k<<<(E + 255) / 256, 256, 0, stream>>>(dst, counts, E);
  scan_k<<<1, 1024, 0, stream>>>(counts, rowptr, dinv, N);
  hipMemcpyAsync(cursor, rowptr, (size_t)N * sizeof(int), hipMemcpyDeviceToDevice, stream);
  fill_k<<<(E + 255) / 256, 256, 0, stream>>>(src, dst, cursor, csr_src, E);

  // ----- layer 1 -----
  gemm128_k<<<(N + 63) / 64, 256, 0, stream>>>(x, W1e, bufA, N);
  agg_gather_k<<<(N + 3) / 4, 256, 0, stream>>>(rowptr, csr_src, dinv, bufA, bufB, N);

  // ----- layer 2 -----
  gemm128_k<<<(N + 63) / 64, 256, 0, stream>>>(bufB, W2e, bufA, N);
  agg_gather_k<<<(N + 3) / 4, 256, 0, stream>>>(rowptr, csr_src, dinv, bufA, bufB, N);

  // ----- classifier -----
  logits_k<<<(N + 255) / 256, 256, 0, stream>>>(bufB, lw, lb, out, N);
}

// Round 4
// 435.965 us; speedup vs baseline: 6.8700x; 1.2425x over previous
//
#include <hip/hip_runtime.h>
#include <cstddef>
#include <cstdint>

#define F 128
#define C_OUT 10
#define SB 256   // scan block size

// ---------------- GRU weight evolution: W' = GRU(W0, W0) ----------------
__global__ void gru_evolve_k(const float* __restrict__ W0,
                             const float* __restrict__ wih,
                             const float* __restrict__ whh,
                             const float* __restrict__ bih,
                             const float* __restrict__ bhh,
                             float* __restrict__ Wout) {
  int t = blockIdx.x * blockDim.x + threadIdx.x;   // 0..16383
  int i = t >> 7, j = t & 127;
  const float4* w0r = (const float4*)(W0 + (size_t)i * F);
  float gi[3], gh[3];
#pragma unroll
  for (int g = 0; g < 3; ++g) {
    const float4* wr = (const float4*)(wih + (size_t)(g * F + j) * F);
    const float4* hr = (const float4*)(whh + (size_t)(g * F + j) * F);
    float si = 0.f, sh = 0.f;
    for (int k = 0; k < F / 4; ++k) {
      float4 a = w0r[k];
      float4 b = wr[k];
      float4 c = hr[k];
      si += a.x * b.x + a.y * b.y + a.z * b.z + a.w * b.w;
      sh += a.x * c.x + a.y * c.y + a.z * c.z + a.w * c.w;
    }
    gi[g] = si + bih[g * F + j];
    gh[g] = sh + bhh[g * F + j];
  }
  float r = 1.0f / (1.0f + expf(-(gi[0] + gh[0])));
  float z = 1.0f / (1.0f + expf(-(gi[1] + gh[1])));
  float n = tanhf(gi[2] + r * gh[2]);
  Wout[(size_t)i * F + j] = (1.0f - z) * n + z * W0[(size_t)i * F + j];
}

// ---------------- CSR build ----------------
__global__ void count_k(const int* __restrict__ dst, int* __restrict__ counts, int E) {
  int e = blockIdx.x * blockDim.x + threadIdx.x;
  if (e < E) atomicAdd(&counts[dst[e]], 1);
}

// Phase 1: per-256-block inclusive scan; write inclusive values + block totals.
__global__ void scan_local_k(const int* __restrict__ counts, int* __restrict__ incl,
                             int* __restrict__ blocksum, int n) {
  __shared__ int sh[SB];
  int gid = blockIdx.x * SB + threadIdx.x;
  int v = (gid < n) ? counts[gid] : 0;
  sh[threadIdx.x] = v;
  __syncthreads();
  for (int off = 1; off < SB; off <<= 1) {
    int t = 0;
    if ((int)threadIdx.x >= off) t = sh[threadIdx.x - off];
    __syncthreads();
    if ((int)threadIdx.x >= off) sh[threadIdx.x] += t;
    __syncthreads();
  }
  if (gid < n) incl[gid] = sh[threadIdx.x];
  if (threadIdx.x == SB - 1) blocksum[blockIdx.x] = sh[SB - 1];
}

// Phase 2: single block scans block totals (nb <= 256) -> exclusive offsets.
__global__ void scan_blocks_k(int* __restrict__ blocksum, int nb) {
  __shared__ int sh[SB];
  int v = ((int)threadIdx.x < nb) ? blocksum[threadIdx.x] : 0;
  sh[threadIdx.x] = v;
  __syncthreads();
  for (int off = 1; off < SB; off <<= 1) {
    int t = 0;
    if ((int)threadIdx.x >= off) t = sh[threadIdx.x - off];
    __syncthreads();
    if ((int)threadIdx.x >= off) sh[threadIdx.x] += t;
    __syncthreads();
  }
  if ((int)threadIdx.x < nb) blocksum[threadIdx.x] = sh[threadIdx.x] - v;  // exclusive
}

// Phase 3: rowptr/cursor/dinv, all parallel.
__global__ void scan_finish_k(const int* __restrict__ counts, const int* __restrict__ incl,
                              const int* __restrict__ blocksum, int* __restrict__ rowptr,
                              int* __restrict__ cursor, float* __restrict__ dinv, int n) {
  int gid = blockIdx.x * SB + threadIdx.x;
  if (gid >= n) return;
  int c = counts[gid];
  int inc = blocksum[blockIdx.x] + incl[gid];
  int excl = inc - c;
  rowptr[gid] = excl;
  cursor[gid] = excl;
  dinv[gid] = rsqrtf((float)c + 1.0f);
  if (gid == n - 1) rowptr[n] = inc;
}

__global__ void fill_k(const int* __restrict__ src, const int* __restrict__ dst,
                       int* __restrict__ cursor, int* __restrict__ csr_src, int E) {
  int e = blockIdx.x * blockDim.x + threadIdx.x;
  if (e < E) {
    int d = dst[e];
    int pos = atomicAdd(&cursor[d], 1);
    csr_src[pos] = src[e];
  }
}

// ---------------- Y = X @ W  (X: nrows x 128, W: 128 x 128) ----------------
__global__ void gemm128_k(const float* __restrict__ X, const float* __restrict__ W,
                          float* __restrict__ Y, int nrows) {
  int lane = threadIdx.x & 63;
  int j0 = __builtin_amdgcn_readfirstlane((int)(threadIdx.x >> 6) * 32);
  int row = blockIdx.x * 64 + lane;
  if (row >= nrows) return;
  float4 acc[8];
#pragma unroll
  for (int jj = 0; jj < 8; ++jj) acc[jj] = make_float4(0.f, 0.f, 0.f, 0.f);
  const float* xr = X + (size_t)row * F;
  for (int k = 0; k < F; k += 4) {
    float4 xk = *(const float4*)(xr + k);
#pragma unroll
    for (int kk = 0; kk < 4; ++kk) {
      float xv = (kk == 0) ? xk.x : (kk == 1) ? xk.y : (kk == 2) ? xk.z : xk.w;
      const float4* wr = (const float4*)(W + (size_t)(k + kk) * F + j0);
#pragma unroll
      for (int jj = 0; jj < 8; ++jj) {
        float4 w4 = wr[jj];
        acc[jj].x = fmaf(xv, w4.x, acc[jj].x);
        acc[jj].y = fmaf(xv, w4.y, acc[jj].y);
        acc[jj].z = fmaf(xv, w4.z, acc[jj].z);
        acc[jj].w = fmaf(xv, w4.w, acc[jj].w);
      }
    }
  }
  float4* yr = (float4*)(Y + (size_t)row * F + j0);
#pragma unroll
  for (int jj = 0; jj < 8; ++jj) yr[jj] = acc[jj];
}

// ---------------- gather aggregation + self-loop + relu ----------------
__global__ void agg_gather_k(const int* __restrict__ rowptr, const int* __restrict__ csr_src,
                             const float* __restrict__ dinv, const float* __restrict__ xw,
                             float* __restrict__ outp, int n) {
  int wave = (int)((blockIdx.x * blockDim.x + threadIdx.x) >> 6);
  int lane = threadIdx.x & 63;
  if (wave >= n) return;
  int node = __builtin_amdgcn_readfirstlane(wave);
  const float2* __restrict__ xw2 = (const float2*)xw;
  float dd = dinv[node];
  float2 me = xw2[(size_t)node * 64 + lane];
  float accx = dd * dd * me.x;
  float accy = dd * dd * me.y;
  int b = rowptr[node], e = rowptr[node + 1];
  int i = b;
  for (; i + 8 <= e; i += 8) {
    int s0 = csr_src[i + 0], s1 = csr_src[i + 1], s2 = csr_src[i + 2], s3 = csr_src[i + 3];
    int s4 = csr_src[i + 4], s5 = csr_src[i + 5], s6 = csr_src[i + 6], s7 = csr_src[i + 7];
    float w0 = dinv[s0], w1 = dinv[s1], w2 = dinv[s2], w3 = dinv[s3];
    float w4 = dinv[s4], w5 = dinv[s5], w6 = dinv[s6], w7 = dinv[s7];
    float2 v0 = xw2[(size_t)s0 * 64 + lane];
    float2 v1 = xw2[(size_t)s1 * 64 + lane];
    float2 v2 = xw2[(size_t)s2 * 64 + lane];
    float2 v3 = xw2[(size_t)s3 * 64 + lane];
    float2 v4 = xw2[(size_t)s4 * 64 + lane];
    float2 v5 = xw2[(size_t)s5 * 64 + lane];
    float2 v6 = xw2[(size_t)s6 * 64 + lane];
    float2 v7 = xw2[(size_t)s7 * 64 + lane];
    accx = fmaf(dd * w0, v0.x, accx); accy = fmaf(dd * w0, v0.y, accy);
    accx = fmaf(dd * w1, v1.x, accx); accy = fmaf(dd * w1, v1.y, accy);
    accx = fmaf(dd * w2, v2.x, accx); accy = fmaf(dd * w2, v2.y, accy);
    accx = fmaf(dd * w3, v3.x, accx); accy = fmaf(dd * w3, v3.y, accy);
    accx = fmaf(dd * w4, v4.x, accx); accy = fmaf(dd * w4, v4.y, accy);
    accx = fmaf(dd * w5, v5.x, accx); accy = fmaf(dd * w5, v5.y, accy);
    accx = fmaf(dd * w6, v6.x, accx); accy = fmaf(dd * w6, v6.y, accy);
    accx = fmaf(dd * w7, v7.x, accx); accy = fmaf(dd * w7, v7.y, accy);
  }
  for (; i < e; ++i) {
    int s = csr_src[i];
    float w = dinv[s];
    float2 v = xw2[(size_t)s * 64 + lane];
    accx = fmaf(dd * w, v.x, accx);
    accy = fmaf(dd * w, v.y, accy);
  }
  float2 r;
  r.x = fmaxf(accx, 0.f);
  r.y = fmaxf(accy, 0.f);
  ((float2*)outp)[(size_t)node * 64 + lane] = r;
}

// ---------------- logits + log_softmax ----------------
__global__ void logits_k(const float* __restrict__ h, const float* __restrict__ lw,
                         const float* __restrict__ lb, float* __restrict__ out, int n) {
  int i = blockIdx.x * blockDim.x + threadIdx.x;
  if (i >= n) return;
  float acc[C_OUT];
#pragma unroll
  for (int c = 0; c < C_OUT; ++c) acc[c] = lb[c];
  const float4* hr = (const float4*)(h + (size_t)i * F);
  for (int k = 0; k < F / 4; ++k) {
    float4 hv = hr[k];
#pragma unroll
    for (int c = 0; c < C_OUT; ++c) {
      float4 w = *(const float4*)(lw + (size_t)c * F + k * 4);
      acc[c] += hv.x * w.x + hv.y * w.y + hv.z * w.z + hv.w * w.w;
    }
  }
  float m = acc[0];
#pragma unroll
  for (int c = 1; c < C_OUT; ++c) m = fmaxf(m, acc[c]);
  float s = 0.f;
#pragma unroll
  for (int c = 0; c < C_OUT; ++c) s += expf(acc[c] - m);
  float lse = m + logf(s);
#pragma unroll
  for (int c = 0; c < C_OUT; ++c) out[(size_t)i * C_OUT + c] = acc[c] - lse;
}

extern "C" void kernel_launch(void* const* d_in, const int* in_sizes, int n_in,
                              void* d_out, int out_size, void* d_ws, size_t ws_size,
                              hipStream_t stream) {
  const float* x    = (const float*)d_in[0];
  const int*   ei   = (const int*)d_in[1];
  const float* W1   = (const float*)d_in[2];
  const float* wih1 = (const float*)d_in[3];
  const float* whh1 = (const float*)d_in[4];
  const float* bih1 = (const float*)d_in[5];
  const float* bhh1 = (const float*)d_in[6];
  const float* W2   = (const float*)d_in[7];
  const float* wih2 = (const float*)d_in[8];
  const float* whh2 = (const float*)d_in[9];
  const float* bih2 = (const float*)d_in[10];
  const float* bhh2 = (const float*)d_in[11];
  const float* lw   = (const float*)d_in[12];
  const float* lb   = (const float*)d_in[13];
  float* out = (float*)d_out;

  int N = in_sizes[0] / F;
  int E = in_sizes[1] / 2;
  const int* src = ei;
  const int* dst = ei + E;
  int nb = (N + SB - 1) / SB;   // 196 for N=50000 (must be <= 256)

  float* ws   = (float*)d_ws;
  float* bufA = ws;                        // N*F  (xw)
  float* bufB = bufA + (size_t)N * F;      // N*F  (h)
  float* dinv = bufB + (size_t)N * F;      // N
  float* W1e  = dinv + N;                  // F*F
  float* W2e  = W1e + F * F;               // F*F
  int* counts = (int*)(W2e + F * F);       // N
  int* rowptr = counts + N;                // N+1
  int* cursor = rowptr + N + 1;            // N
  int* incl   = cursor + N;                // N
  int* blocksum = incl + N;                // nb (<=256)
  int* csr_src = blocksum + 256;           // E

  // evolve weights (tiny)
  gru_evolve_k<<<(F * F) / 256, 256, 0, stream>>>(W1, wih1, whh1, bih1, bhh1, W1e);
  gru_evolve_k<<<(F * F) / 256, 256, 0, stream>>>(W2, wih2, whh2, bih2, bhh2, W2e);

  // ----- CSR build + normalization (parallel scan) -----
  hipMemsetAsync(counts, 0, (size_t)N * sizeof(int), stream);
  count_k<<<(E + 255) / 256, 256, 0, stream>>>(dst, counts, E);
  scan_local_k<<<nb, SB, 0, stream>>>(counts, incl, blocksum, N);
  scan_blocks_k<<<1, SB, 0, stream>>>(blocksum, nb);
  scan_finish_k<<<nb, SB, 0, stream>>>(counts, incl, blocksum, rowptr, cursor, dinv, N);
  fill_k<<<(E + 255) / 256, 256, 0, stream>>>(src, dst, cursor, csr_src, E);

  // ----- layer 1 -----
  gemm128_k<<<(N + 63) / 64, 256, 0, stream>>>(x, W1e, bufA, N);
  agg_gather_k<<<(N + 3) / 4, 256, 0, stream>>>(rowptr, csr_src, dinv, bufA, bufB, N);

  // ----- layer 2 -----
  gemm128_k<<<(N + 63) / 64, 256, 0, stream>>>(bufB, W2e, bufA, N);
  agg_gather_k<<<(N + 3) / 4, 256, 0, stream>>>(rowptr, csr_src, dinv, bufA, bufB, N);

  // ----- classifier -----
  logits_k<<<(N + 255) / 256, 256, 0, stream>>>(bufB, lw, lb, out, N);
}

// Round 5
// 371.420 us; speedup vs baseline: 8.0639x; 1.1738x over previous
//
#include <hip/hip_runtime.h>
#include <cstddef>
#include <cstdint>

#define F 128
#define C_OUT 10
#define SB 256   // scan block size

// ---- bf16x2 pack/unpack (RNE) ----
__device__ __forceinline__ unsigned pack_bf16x2(float a, float b) {
  unsigned ua = __float_as_uint(a);
  unsigned ub = __float_as_uint(b);
  ua = (ua + 0x7FFFu + ((ua >> 16) & 1u)) >> 16;
  ub = (ub + 0x7FFFu + ((ub >> 16) & 1u)) >> 16;
  return ua | (ub << 16);
}
__device__ __forceinline__ float unpk_lo(unsigned p) { return __uint_as_float(p << 16); }
__device__ __forceinline__ float unpk_hi(unsigned p) { return __uint_as_float(p & 0xFFFF0000u); }

// ---------------- GRU weight evolution (both layers) + zero counts ----------------
// blocks [0,128): gru for layer1/layer2 ; blocks [128, 128+nbz): zero counts
__global__ void gru_evolve2_k(const float* __restrict__ W01, const float* __restrict__ wih1,
                              const float* __restrict__ whh1, const float* __restrict__ bih1,
                              const float* __restrict__ bhh1,
                              const float* __restrict__ W02, const float* __restrict__ wih2,
                              const float* __restrict__ whh2, const float* __restrict__ bih2,
                              const float* __restrict__ bhh2,
                              float* __restrict__ W1e, float* __restrict__ W2e,
                              int* __restrict__ counts, int n) {
  if ((int)blockIdx.x >= 128) {
    int i = ((int)blockIdx.x - 128) * SB + threadIdx.x;
    if (i < n) counts[i] = 0;
    return;
  }
  int t = blockIdx.x * 256 + threadIdx.x;     // 0..32767
  int layer = t >> 14;
  int tt = t & 16383;
  const float* W0  = layer ? W02  : W01;
  const float* wih = layer ? wih2 : wih1;
  const float* whh = layer ? whh2 : whh1;
  const float* bih = layer ? bih2 : bih1;
  const float* bhh = layer ? bhh2 : bhh1;
  float* Wout = layer ? W2e : W1e;
  int i = tt >> 7, j = tt & 127;
  const float4* w0r = (const float4*)(W0 + (size_t)i * F);
  float gi[3], gh[3];
#pragma unroll
  for (int g = 0; g < 3; ++g) {
    const float4* wr = (const float4*)(wih + (size_t)(g * F + j) * F);
    const float4* hr = (const float4*)(whh + (size_t)(g * F + j) * F);
    float si = 0.f, sh = 0.f;
    for (int k = 0; k < F / 4; ++k) {
      float4 a = w0r[k];
      float4 b = wr[k];
      float4 c = hr[k];
      si += a.x * b.x + a.y * b.y + a.z * b.z + a.w * b.w;
      sh += a.x * c.x + a.y * c.y + a.z * c.z + a.w * c.w;
    }
    gi[g] = si + bih[g * F + j];
    gh[g] = sh + bhh[g * F + j];
  }
  float r = 1.0f / (1.0f + expf(-(gi[0] + gh[0])));
  float z = 1.0f / (1.0f + expf(-(gi[1] + gh[1])));
  float nn = tanhf(gi[2] + r * gh[2]);
  Wout[(size_t)i * F + j] = (1.0f - z) * nn + z * W0[(size_t)i * F + j];
}

// ---------------- CSR build ----------------
__global__ void count_k(const int* __restrict__ dst, int* __restrict__ counts, int E) {
  int e = blockIdx.x * blockDim.x + threadIdx.x;
  if (e < E) atomicAdd(&counts[dst[e]], 1);
}

__global__ void scan_local_k(const int* __restrict__ counts, int* __restrict__ incl,
                             int* __restrict__ blocksum, int n) {
  __shared__ int sh[SB];
  int gid = blockIdx.x * SB + threadIdx.x;
  int v = (gid < n) ? counts[gid] : 0;
  sh[threadIdx.x] = v;
  __syncthreads();
  for (int off = 1; off < SB; off <<= 1) {
    int t = 0;
    if ((int)threadIdx.x >= off) t = sh[threadIdx.x - off];
    __syncthreads();
    if ((int)threadIdx.x >= off) sh[threadIdx.x] += t;
    __syncthreads();
  }
  if (gid < n) incl[gid] = sh[threadIdx.x];
  if (threadIdx.x == SB - 1) blocksum[blockIdx.x] = sh[SB - 1];
}

__global__ void scan_blocks_k(int* __restrict__ blocksum, int nb) {
  __shared__ int sh[SB];
  int v = ((int)threadIdx.x < nb) ? blocksum[threadIdx.x] : 0;
  sh[threadIdx.x] = v;
  __syncthreads();
  for (int off = 1; off < SB; off <<= 1) {
    int t = 0;
    if ((int)threadIdx.x >= off) t = sh[threadIdx.x - off];
    __syncthreads();
    if ((int)threadIdx.x >= off) sh[threadIdx.x] += t;
    __syncthreads();
  }
  if ((int)threadIdx.x < nb) blocksum[threadIdx.x] = sh[threadIdx.x] - v;  // exclusive
}

__global__ void scan_finish_k(const int* __restrict__ counts, const int* __restrict__ incl,
                              const int* __restrict__ blocksum, int* __restrict__ rowptr,
                              int* __restrict__ cursor, float* __restrict__ dinv, int n) {
  int gid = blockIdx.x * SB + threadIdx.x;
  if (gid >= n) return;
  int c = counts[gid];
  int inc = blocksum[blockIdx.x] + incl[gid];
  int excl = inc - c;
  rowptr[gid] = excl;
  cursor[gid] = excl;
  dinv[gid] = rsqrtf((float)c + 1.0f);
  if (gid == n - 1) rowptr[n] = inc;
}

__global__ void fill_k(const int* __restrict__ src, const int* __restrict__ dst,
                       int* __restrict__ cursor, int* __restrict__ csr_src, int E) {
  int e = blockIdx.x * blockDim.x + threadIdx.x;
  if (e < E) {
    int d = dst[e];
    int pos = atomicAdd(&cursor[d], 1);
    csr_src[pos] = src[e];
  }
}

// ---------------- Y' = bf16(dinv[row] * (X @ W))  packed 2 cols/uint ----------------
__global__ void gemm128_bf16_k(const float* __restrict__ X, const float* __restrict__ W,
                               const float* __restrict__ dinv, unsigned* __restrict__ Y,
                               int nrows) {
  int lane = threadIdx.x & 63;
  int j0 = __builtin_amdgcn_readfirstlane((int)(threadIdx.x >> 6) * 32);
  int row = blockIdx.x * 64 + lane;
  if (row >= nrows) return;
  float4 acc[8];
#pragma unroll
  for (int jj = 0; jj < 8; ++jj) acc[jj] = make_float4(0.f, 0.f, 0.f, 0.f);
  const float* xr = X + (size_t)row * F;
  for (int k = 0; k < F; k += 4) {
    float4 xk = *(const float4*)(xr + k);
#pragma unroll
    for (int kk = 0; kk < 4; ++kk) {
      float xv = (kk == 0) ? xk.x : (kk == 1) ? xk.y : (kk == 2) ? xk.z : xk.w;
      const float4* wr = (const float4*)(W + (size_t)(k + kk) * F + j0);
#pragma unroll
      for (int jj = 0; jj < 8; ++jj) {
        float4 w4 = wr[jj];
        acc[jj].x = fmaf(xv, w4.x, acc[jj].x);
        acc[jj].y = fmaf(xv, w4.y, acc[jj].y);
        acc[jj].z = fmaf(xv, w4.z, acc[jj].z);
        acc[jj].w = fmaf(xv, w4.w, acc[jj].w);
      }
    }
  }
  float dd = dinv[row];
  uint4* yv = (uint4*)(Y + (size_t)row * 64 + (j0 >> 1));
#pragma unroll
  for (int q = 0; q < 4; ++q) {
    float4 a = acc[q * 2], b = acc[q * 2 + 1];
    uint4 o;
    o.x = pack_bf16x2(dd * a.x, dd * a.y);
    o.y = pack_bf16x2(dd * a.z, dd * a.w);
    o.z = pack_bf16x2(dd * b.x, dd * b.y);
    o.w = pack_bf16x2(dd * b.z, dd * b.w);
    yv[q] = o;
  }
}

// ---------------- gather aggregation (+ optional fused logits/log_softmax) ----------------
// One wave per node; lane owns cols {2*lane, 2*lane+1}. Rows are pre-scaled by dinv[src],
// so the edge loop is pure adds: h = relu(dd * (xw'[node] + sum xw'[s])).
template <bool FUSE_LOGITS>
__global__ void agg_bf16_k(const int* __restrict__ rowptr, const int* __restrict__ csr_src,
                           const float* __restrict__ dinv, const unsigned* __restrict__ xwp,
                           float* __restrict__ hout,
                           const float* __restrict__ lw, const float* __restrict__ lb,
                           float* __restrict__ outp, int n) {
  int wave = (int)((blockIdx.x * blockDim.x + threadIdx.x) >> 6);
  int lane = threadIdx.x & 63;
  if (wave >= n) return;
  int node = __builtin_amdgcn_readfirstlane(wave);
  float dd = dinv[node];
  unsigned um = xwp[(size_t)node * 64 + lane];
  float accx = unpk_lo(um), accy = unpk_hi(um);
  int b = rowptr[node], e = rowptr[node + 1];
  int i = b;
  for (; i + 8 <= e; i += 8) {
    int s0 = csr_src[i + 0], s1 = csr_src[i + 1], s2 = csr_src[i + 2], s3 = csr_src[i + 3];
    int s4 = csr_src[i + 4], s5 = csr_src[i + 5], s6 = csr_src[i + 6], s7 = csr_src[i + 7];
    unsigned u0 = xwp[(size_t)s0 * 64 + lane];
    unsigned u1 = xwp[(size_t)s1 * 64 + lane];
    unsigned u2 = xwp[(size_t)s2 * 64 + lane];
    unsigned u3 = xwp[(size_t)s3 * 64 + lane];
    unsigned u4 = xwp[(size_t)s4 * 64 + lane];
    unsigned u5 = xwp[(size_t)s5 * 64 + lane];
    unsigned u6 = xwp[(size_t)s6 * 64 + lane];
    unsigned u7 = xwp[(size_t)s7 * 64 + lane];
    accx += unpk_lo(u0); accy += unpk_hi(u0);
    accx += unpk_lo(u1); accy += unpk_hi(u1);
    accx += unpk_lo(u2); accy += unpk_hi(u2);
    accx += unpk_lo(u3); accy += unpk_hi(u3);
    accx += unpk_lo(u4); accy += unpk_hi(u4);
    accx += unpk_lo(u5); accy += unpk_hi(u5);
    accx += unpk_lo(u6); accy += unpk_hi(u6);
    accx += unpk_lo(u7); accy += unpk_hi(u7);
  }
  for (; i + 2 <= e; i += 2) {
    int s0 = csr_src[i + 0], s1 = csr_src[i + 1];
    unsigned u0 = xwp[(size_t)s0 * 64 + lane];
    unsigned u1 = xwp[(size_t)s1 * 64 + lane];
    accx += unpk_lo(u0); accy += unpk_hi(u0);
    accx += unpk_lo(u1); accy += unpk_hi(u1);
  }
  if (i < e) {
    int s = csr_src[i];
    unsigned u = xwp[(size_t)s * 64 + lane];
    accx += unpk_lo(u); accy += unpk_hi(u);
  }
  float hx = fmaxf(dd * accx, 0.f);
  float hy = fmaxf(dd * accy, 0.f);
  if (!FUSE_LOGITS) {
    float2 r; r.x = hx; r.y = hy;
    ((float2*)hout)[(size_t)node * 64 + lane] = r;
  } else {
    float acc[C_OUT];
    const float2* lw2 = (const float2*)lw;
#pragma unroll
    for (int c = 0; c < C_OUT; ++c) {
      float2 w = lw2[(size_t)c * 64 + lane];
      float v = hx * w.x + hy * w.y;
#pragma unroll
      for (int off = 1; off < 64; off <<= 1) v += __shfl_xor(v, off);
      acc[c] = v + lb[c];
    }
    float m = acc[0];
#pragma unroll
    for (int c = 1; c < C_OUT; ++c) m = fmaxf(m, acc[c]);
    float s = 0.f;
#pragma unroll
    for (int c = 0; c < C_OUT; ++c) s += expf(acc[c] - m);
    float lse = m + logf(s);
#pragma unroll
    for (int c = 0; c < C_OUT; ++c)
      if (lane == c) outp[(size_t)node * C_OUT + c] = acc[c] - lse;
  }
}

extern "C" void kernel_launch(void* const* d_in, const int* in_sizes, int n_in,
                              void* d_out, int out_size, void* d_ws, size_t ws_size,
                              hipStream_t stream) {
  const float* x    = (const float*)d_in[0];
  const int*   ei   = (const int*)d_in[1];
  const float* W1   = (const float*)d_in[2];
  const float* wih1 = (const float*)d_in[3];
  const float* whh1 = (const float*)d_in[4];
  const float* bih1 = (const float*)d_in[5];
  const float* bhh1 = (const float*)d_in[6];
  const float* W2   = (const float*)d_in[7];
  const float* wih2 = (const float*)d_in[8];
  const float* whh2 = (const float*)d_in[9];
  const float* bih2 = (const float*)d_in[10];
  const float* bhh2 = (const float*)d_in[11];
  const float* lw   = (const float*)d_in[12];
  const float* lb   = (const float*)d_in[13];
  float* out = (float*)d_out;

  int N = in_sizes[0] / F;
  int E = in_sizes[1] / 2;
  const int* src = ei;
  const int* dst = ei + E;
  int nb = (N + SB - 1) / SB;   // 196 for N=50000 (must be <= 256)

  float* ws   = (float*)d_ws;
  unsigned* bufA = (unsigned*)ws;          // N*64 uints (bf16x2 xw')
  float* bufB = ws + (size_t)N * F;        // N*F  (h fp32)
  float* dinv = bufB + (size_t)N * F;      // N
  float* W1e  = dinv + N;                  // F*F
  float* W2e  = W1e + F * F;               // F*F
  int* counts = (int*)(W2e + F * F);       // N
  int* rowptr = counts + N;                // N+1
  int* cursor = rowptr + N + 1;            // N
  int* incl   = cursor + N;                // N
  int* blocksum = incl + N;                // nb (<=256)
  int* csr_src = blocksum + 256;           // E

  // evolve weights (both layers) + zero counts
  gru_evolve2_k<<<128 + nb, 256, 0, stream>>>(W1, wih1, whh1, bih1, bhh1,
                                              W2, wih2, whh2, bih2, bhh2,
                                              W1e, W2e, counts, N);

  // ----- CSR build + normalization (parallel scan) -----
  count_k<<<(E + 255) / 256, 256, 0, stream>>>(dst, counts, E);
  scan_local_k<<<nb, SB, 0, stream>>>(counts, incl, blocksum, N);
  scan_blocks_k<<<1, SB, 0, stream>>>(blocksum, nb);
  scan_finish_k<<<nb, SB, 0, stream>>>(counts, incl, blocksum, rowptr, cursor, dinv, N);
  fill_k<<<(E + 255) / 256, 256, 0, stream>>>(src, dst, cursor, csr_src, E);

  // ----- layer 1 -----
  gemm128_bf16_k<<<(N + 63) / 64, 256, 0, stream>>>(x, W1e, dinv, bufA, N);
  agg_bf16_k<false><<<(N + 3) / 4, 256, 0, stream>>>(rowptr, csr_src, dinv, bufA, bufB,
                                                     nullptr, nullptr, nullptr, N);

  // ----- layer 2 (logits fused) -----
  gemm128_bf16_k<<<(N + 63) / 64, 256, 0, stream>>>(bufB, W2e, dinv, bufA, N);
  agg_bf16_k<true><<<(N + 3) / 4, 256, 0, stream>>>(rowptr, csr_src, dinv, bufA, nullptr,
                                                    lw, lb, out, N);
}

// Round 6
// 336.875 us; speedup vs baseline: 8.8908x; 1.1025x over previous
//
#include <hip/hip_runtime.h>
#include <cstddef>
#include <cstdint>

#define F 128
#define C_OUT 10
#define SB 256   // scan block size

// ---- bf16x2 pack/unpack (RNE) ----
__device__ __forceinline__ unsigned pack_bf16x2(float a, float b) {
  unsigned ua = __float_as_uint(a);
  unsigned ub = __float_as_uint(b);
  ua = (ua + 0x7FFFu + ((ua >> 16) & 1u)) >> 16;
  ub = (ub + 0x7FFFu + ((ub >> 16) & 1u)) >> 16;
  return ua | (ub << 16);
}
__device__ __forceinline__ float unpk_lo(unsigned p) { return __uint_as_float(p << 16); }
__device__ __forceinline__ float unpk_hi(unsigned p) { return __uint_as_float(p & 0xFFFF0000u); }

// ---------------- GRU weight evolution (both layers) + zero counts ----------------
// blocks [0,128): gru for layer1/layer2 ; blocks [128, 128+nbz): zero counts
__global__ void gru_evolve2_k(const float* __restrict__ W01, const float* __restrict__ wih1,
                              const float* __restrict__ whh1, const float* __restrict__ bih1,
                              const float* __restrict__ bhh1,
                              const float* __restrict__ W02, const float* __restrict__ wih2,
                              const float* __restrict__ whh2, const float* __restrict__ bih2,
                              const float* __restrict__ bhh2,
                              float* __restrict__ W1e, float* __restrict__ W2e,
                              int* __restrict__ counts, int n) {
  if ((int)blockIdx.x >= 128) {
    int i = ((int)blockIdx.x - 128) * SB + threadIdx.x;
    if (i < n) counts[i] = 0;
    return;
  }
  int t = blockIdx.x * 256 + threadIdx.x;     // 0..32767
  int layer = t >> 14;
  int tt = t & 16383;
  const float* W0  = layer ? W02  : W01;
  const float* wih = layer ? wih2 : wih1;
  const float* whh = layer ? whh2 : whh1;
  const float* bih = layer ? bih2 : bih1;
  const float* bhh = layer ? bhh2 : bhh1;
  float* Wout = layer ? W2e : W1e;
  int i = tt >> 7, j = tt & 127;
  const float4* w0r = (const float4*)(W0 + (size_t)i * F);
  float gi[3], gh[3];
#pragma unroll
  for (int g = 0; g < 3; ++g) {
    const float4* wr = (const float4*)(wih + (size_t)(g * F + j) * F);
    const float4* hr = (const float4*)(whh + (size_t)(g * F + j) * F);
    float si = 0.f, sh = 0.f;
    for (int k = 0; k < F / 4; ++k) {
      float4 a = w0r[k];
      float4 b = wr[k];
      float4 c = hr[k];
      si += a.x * b.x + a.y * b.y + a.z * b.z + a.w * b.w;
      sh += a.x * c.x + a.y * c.y + a.z * c.z + a.w * c.w;
    }
    gi[g] = si + bih[g * F + j];
    gh[g] = sh + bhh[g * F + j];
  }
  float r = 1.0f / (1.0f + expf(-(gi[0] + gh[0])));
  float z = 1.0f / (1.0f + expf(-(gi[1] + gh[1])));
  float nn = tanhf(gi[2] + r * gh[2]);
  Wout[(size_t)i * F + j] = (1.0f - z) * nn + z * W0[(size_t)i * F + j];
}

// ---------------- CSR build ----------------
// count + per-edge rank in one pass: the atomic's return value (previously
// discarded) is the edge's slot within its destination row.
__global__ void count_rank_k(const int* __restrict__ dst, int* __restrict__ counts,
                             int* __restrict__ rank, int E) {
  int e = blockIdx.x * blockDim.x + threadIdx.x;
  if (e < E) rank[e] = atomicAdd(&counts[dst[e]], 1);
}

__global__ void scan_local_k(const int* __restrict__ counts, int* __restrict__ incl,
                             int* __restrict__ blocksum, int n) {
  __shared__ int sh[SB];
  int gid = blockIdx.x * SB + threadIdx.x;
  int v = (gid < n) ? counts[gid] : 0;
  sh[threadIdx.x] = v;
  __syncthreads();
  for (int off = 1; off < SB; off <<= 1) {
    int t = 0;
    if ((int)threadIdx.x >= off) t = sh[threadIdx.x - off];
    __syncthreads();
    if ((int)threadIdx.x >= off) sh[threadIdx.x] += t;
    __syncthreads();
  }
  if (gid < n) incl[gid] = sh[threadIdx.x];
  if (threadIdx.x == SB - 1) blocksum[blockIdx.x] = sh[SB - 1];
}

__global__ void scan_blocks_k(int* __restrict__ blocksum, int nb) {
  __shared__ int sh[SB];
  int v = ((int)threadIdx.x < nb) ? blocksum[threadIdx.x] : 0;
  sh[threadIdx.x] = v;
  __syncthreads();
  for (int off = 1; off < SB; off <<= 1) {
    int t = 0;
    if ((int)threadIdx.x >= off) t = sh[threadIdx.x - off];
    __syncthreads();
    if ((int)threadIdx.x >= off) sh[threadIdx.x] += t;
    __syncthreads();
  }
  if ((int)threadIdx.x < nb) blocksum[threadIdx.x] = sh[threadIdx.x] - v;  // exclusive
}

__global__ void scan_finish_k(const int* __restrict__ counts, const int* __restrict__ incl,
                              const int* __restrict__ blocksum, int* __restrict__ rowptr,
                              float* __restrict__ dinv, int n) {
  int gid = blockIdx.x * SB + threadIdx.x;
  if (gid >= n) return;
  int c = counts[gid];
  int inc = blocksum[blockIdx.x] + incl[gid];
  rowptr[gid] = inc - c;
  dinv[gid] = rsqrtf((float)c + 1.0f);
  if (gid == n - 1) rowptr[n] = inc;
}

// atomic-free fill: slot = rowptr[dst] + rank.
__global__ void fill_k(const int* __restrict__ src, const int* __restrict__ dst,
                       const int* __restrict__ rank, const int* __restrict__ rowptr,
                       int* __restrict__ csr_src, int E) {
  int e = blockIdx.x * blockDim.x + threadIdx.x;
  if (e < E) {
    int d = dst[e];
    csr_src[rowptr[d] + rank[e]] = src[e];
  }
}

// ---------------- Y' = bf16(dinv[row] * (X @ W))  packed 2 cols/uint ----------------
__global__ void gemm128_bf16_k(const float* __restrict__ X, const float* __restrict__ W,
                               const float* __restrict__ dinv, unsigned* __restrict__ Y,
                               int nrows) {
  int lane = threadIdx.x & 63;
  int j0 = __builtin_amdgcn_readfirstlane((int)(threadIdx.x >> 6) * 32);
  int row = blockIdx.x * 64 + lane;
  if (row >= nrows) return;
  float4 acc[8];
#pragma unroll
  for (int jj = 0; jj < 8; ++jj) acc[jj] = make_float4(0.f, 0.f, 0.f, 0.f);
  const float* xr = X + (size_t)row * F;
  for (int k = 0; k < F; k += 4) {
    float4 xk = *(const float4*)(xr + k);
#pragma unroll
    for (int kk = 0; kk < 4; ++kk) {
      float xv = (kk == 0) ? xk.x : (kk == 1) ? xk.y : (kk == 2) ? xk.z : xk.w;
      const float4* wr = (const float4*)(W + (size_t)(k + kk) * F + j0);
#pragma unroll
      for (int jj = 0; jj < 8; ++jj) {
        float4 w4 = wr[jj];
        acc[jj].x = fmaf(xv, w4.x, acc[jj].x);
        acc[jj].y = fmaf(xv, w4.y, acc[jj].y);
        acc[jj].z = fmaf(xv, w4.z, acc[jj].z);
        acc[jj].w = fmaf(xv, w4.w, acc[jj].w);
      }
    }
  }
  float dd = dinv[row];
  uint4* yv = (uint4*)(Y + (size_t)row * 64 + (j0 >> 1));
#pragma unroll
  for (int q = 0; q < 4; ++q) {
    float4 a = acc[q * 2], b = acc[q * 2 + 1];
    uint4 o;
    o.x = pack_bf16x2(dd * a.x, dd * a.y);
    o.y = pack_bf16x2(dd * a.z, dd * a.w);
    o.z = pack_bf16x2(dd * b.x, dd * b.y);
    o.w = pack_bf16x2(dd * b.z, dd * b.w);
    yv[q] = o;
  }
}

// ---------------- gather aggregation (+ optional fused logits/log_softmax) ----------------
template <bool FUSE_LOGITS>
__global__ void agg_bf16_k(const int* __restrict__ rowptr, const int* __restrict__ csr_src,
                           const float* __restrict__ dinv, const unsigned* __restrict__ xwp,
                           float* __restrict__ hout,
                           const float* __restrict__ lw, const float* __restrict__ lb,
                           float* __restrict__ outp, int n) {
  int wave = (int)((blockIdx.x * blockDim.x + threadIdx.x) >> 6);
  int lane = threadIdx.x & 63;
  if (wave >= n) return;
  int node = __builtin_amdgcn_readfirstlane(wave);
  float dd = dinv[node];
  unsigned um = xwp[(size_t)node * 64 + lane];
  float accx = unpk_lo(um), accy = unpk_hi(um);
  int b = rowptr[node], e = rowptr[node + 1];
  int i = b;
  for (; i + 8 <= e; i += 8) {
    int s0 = csr_src[i + 0], s1 = csr_src[i + 1], s2 = csr_src[i + 2], s3 = csr_src[i + 3];
    int s4 = csr_src[i + 4], s5 = csr_src[i + 5], s6 = csr_src[i + 6], s7 = csr_src[i + 7];
    unsigned u0 = xwp[(size_t)s0 * 64 + lane];
    unsigned u1 = xwp[(size_t)s1 * 64 + lane];
    unsigned u2 = xwp[(size_t)s2 * 64 + lane];
    unsigned u3 = xwp[(size_t)s3 * 64 + lane];
    unsigned u4 = xwp[(size_t)s4 * 64 + lane];
    unsigned u5 = xwp[(size_t)s5 * 64 + lane];
    unsigned u6 = xwp[(size_t)s6 * 64 + lane];
    unsigned u7 = xwp[(size_t)s7 * 64 + lane];
    accx += unpk_lo(u0); accy += unpk_hi(u0);
    accx += unpk_lo(u1); accy += unpk_hi(u1);
    accx += unpk_lo(u2); accy += unpk_hi(u2);
    accx += unpk_lo(u3); accy += unpk_hi(u3);
    accx += unpk_lo(u4); accy += unpk_hi(u4);
    accx += unpk_lo(u5); accy += unpk_hi(u5);
    accx += unpk_lo(u6); accy += unpk_hi(u6);
    accx += unpk_lo(u7); accy += unpk_hi(u7);
  }
  for (; i + 2 <= e; i += 2) {
    int s0 = csr_src[i + 0], s1 = csr_src[i + 1];
    unsigned u0 = xwp[(size_t)s0 * 64 + lane];
    unsigned u1 = xwp[(size_t)s1 * 64 + lane];
    accx += unpk_lo(u0); accy += unpk_hi(u0);
    accx += unpk_lo(u1); accy += unpk_hi(u1);
  }
  if (i < e) {
    int s = csr_src[i];
    unsigned u = xwp[(size_t)s * 64 + lane];
    accx += unpk_lo(u); accy += unpk_hi(u);
  }
  float hx = fmaxf(dd * accx, 0.f);
  float hy = fmaxf(dd * accy, 0.f);
  if (!FUSE_LOGITS) {
    float2 r; r.x = hx; r.y = hy;
    ((float2*)hout)[(size_t)node * 64 + lane] = r;
  } else {
    float acc[C_OUT];
    const float2* lw2 = (const float2*)lw;
#pragma unroll
    for (int c = 0; c < C_OUT; ++c) {
      float2 w = lw2[(size_t)c * 64 + lane];
      float v = hx * w.x + hy * w.y;
#pragma unroll
      for (int off = 1; off < 64; off <<= 1) v += __shfl_xor(v, off);
      acc[c] = v + lb[c];
    }
    float m = acc[0];
#pragma unroll
    for (int c = 1; c < C_OUT; ++c) m = fmaxf(m, acc[c]);
    float s = 0.f;
#pragma unroll
    for (int c = 0; c < C_OUT; ++c) s += expf(acc[c] - m);
    float lse = m + logf(s);
#pragma unroll
    for (int c = 0; c < C_OUT; ++c)
      if (lane == c) outp[(size_t)node * C_OUT + c] = acc[c] - lse;
  }
}

extern "C" void kernel_launch(void* const* d_in, const int* in_sizes, int n_in,
                              void* d_out, int out_size, void* d_ws, size_t ws_size,
                              hipStream_t stream) {
  const float* x    = (const float*)d_in[0];
  const int*   ei   = (const int*)d_in[1];
  const float* W1   = (const float*)d_in[2];
  const float* wih1 = (const float*)d_in[3];
  const float* whh1 = (const float*)d_in[4];
  const float* bih1 = (const float*)d_in[5];
  const float* bhh1 = (const float*)d_in[6];
  const float* W2   = (const float*)d_in[7];
  const float* wih2 = (const float*)d_in[8];
  const float* whh2 = (const float*)d_in[9];
  const float* bih2 = (const float*)d_in[10];
  const float* bhh2 = (const float*)d_in[11];
  const float* lw   = (const float*)d_in[12];
  const float* lb   = (const float*)d_in[13];
  float* out = (float*)d_out;

  int N = in_sizes[0] / F;
  int E = in_sizes[1] / 2;
  const int* src = ei;
  const int* dst = ei + E;
  int nb = (N + SB - 1) / SB;   // 196 for N=50000 (must be <= 256)

  float* ws   = (float*)d_ws;
  unsigned* bufA = (unsigned*)ws;          // N*64 uints (bf16x2 xw')
  float* bufB = ws + (size_t)N * F;        // N*F  (h fp32)
  float* dinv = bufB + (size_t)N * F;      // N
  float* W1e  = dinv + N;                  // F*F
  float* W2e  = W1e + F * F;               // F*F
  int* counts = (int*)(W2e + F * F);       // N
  int* rowptr = counts + N;                // N+1
  int* rank   = rowptr + N + 1;            // E
  int* incl   = rank + E;                  // N
  int* blocksum = incl + N;                // nb (<=256)
  int* csr_src = blocksum + 256;           // E

  // evolve weights (both layers) + zero counts
  gru_evolve2_k<<<128 + nb, 256, 0, stream>>>(W1, wih1, whh1, bih1, bhh1,
                                              W2, wih2, whh2, bih2, bhh2,
                                              W1e, W2e, counts, N);

  // ----- CSR build + normalization (parallel scan) -----
  count_rank_k<<<(E + 255) / 256, 256, 0, stream>>>(dst, counts, rank, E);
  scan_local_k<<<nb, SB, 0, stream>>>(counts, incl, blocksum, N);
  scan_blocks_k<<<1, SB, 0, stream>>>(blocksum, nb);
  scan_finish_k<<<nb, SB, 0, stream>>>(counts, incl, blocksum, rowptr, dinv, N);
  fill_k<<<(E + 255) / 256, 256, 0, stream>>>(src, dst, rank, rowptr, csr_src, E);

  // ----- layer 1 -----
  gemm128_bf16_k<<<(N + 63) / 64, 256, 0, stream>>>(x, W1e, dinv, bufA, N);
  agg_bf16_k<false><<<(N + 3) / 4, 256, 0, stream>>>(rowptr, csr_src, dinv, bufA, bufB,
                                                     nullptr, nullptr, nullptr, N);

  // ----- layer 2 (logits fused) -----
  gemm128_bf16_k<<<(N + 63) / 64, 256, 0, stream>>>(bufB, W2e, dinv, bufA, N);
  agg_bf16_k<true><<<(N + 3) / 4, 256, 0, stream>>>(rowptr, csr_src, dinv, bufA, nullptr,
                                                    lw, lb, out, N);
}

// Round 7
// 311.739 us; speedup vs baseline: 9.6077x; 1.0806x over previous
//
#include <hip/hip_runtime.h>
#include <cstddef>
#include <cstdint>

#define F 128
#define C_OUT 10
#define SB 256   // scan block size

typedef short bf16x8 __attribute__((ext_vector_type(8)));
typedef float f32x4  __attribute__((ext_vector_type(4)));

// ---- bf16 pack helpers ----
__device__ __forceinline__ unsigned pack_bf16x2(float a, float b) {
  unsigned ua = __float_as_uint(a);
  unsigned ub = __float_as_uint(b);
  ua = (ua + 0x7FFFu + ((ua >> 16) & 1u)) >> 16;
  ub = (ub + 0x7FFFu + ((ub >> 16) & 1u)) >> 16;
  return ua | (ub << 16);
}
__device__ __forceinline__ float unpk_lo(unsigned p) { return __uint_as_float(p << 16); }
__device__ __forceinline__ float unpk_hi(unsigned p) { return __uint_as_float(p & 0xFFFF0000u); }
__device__ __forceinline__ unsigned short bf16_rne(float f) {
  unsigned u = __float_as_uint(f);
  return (unsigned short)((u + 0x7FFFu + ((u >> 16) & 1u)) >> 16);
}

// row s of the tiled xwp layout starts (in uints) at:
__device__ __forceinline__ int row_off(int s) {
  return ((s >> 4) << 10) | ((s & 3) << 6) | ((s & 12) << 2);
}

// ---------------- GRU weight evolution (both layers) + zero counts ----------------
// Writes W' split into bf16 hi/lo, pre-packed in MFMA B-fragment order:
//   B[k][n], lane = ((k&31)>>3)*16 + (n&15), j = k&7, kstep = k>>5, tile = n>>4
//   idx = ((kstep*8 + tile)*64 + lane)*8 + j
// blocks [0,128): gru ; blocks [128, 128+nbz): zero counts
__global__ void gru_evolve2_k(const float* __restrict__ W01, const float* __restrict__ wih1,
                              const float* __restrict__ whh1, const float* __restrict__ bih1,
                              const float* __restrict__ bhh1,
                              const float* __restrict__ W02, const float* __restrict__ wih2,
                              const float* __restrict__ whh2, const float* __restrict__ bih2,
                              const float* __restrict__ bhh2,
                              unsigned short* __restrict__ Bhi1, unsigned short* __restrict__ Blo1,
                              unsigned short* __restrict__ Bhi2, unsigned short* __restrict__ Blo2,
                              int* __restrict__ counts, int n) {
  if ((int)blockIdx.x >= 128) {
    int i = ((int)blockIdx.x - 128) * SB + threadIdx.x;
    if (i < n) counts[i] = 0;
    return;
  }
  int t = blockIdx.x * 256 + threadIdx.x;     // 0..32767
  int layer = t >> 14;
  int tt = t & 16383;
  const float* W0  = layer ? W02  : W01;
  const float* wih = layer ? wih2 : wih1;
  const float* whh = layer ? whh2 : whh1;
  const float* bih = layer ? bih2 : bih1;
  const float* bhh = layer ? bhh2 : bhh1;
  unsigned short* Bhi = layer ? Bhi2 : Bhi1;
  unsigned short* Blo = layer ? Blo2 : Blo1;
  int i = tt >> 7, j = tt & 127;      // i = k index, j = n index
  const float4* w0r = (const float4*)(W0 + (size_t)i * F);
  float gi[3], gh[3];
#pragma unroll
  for (int g = 0; g < 3; ++g) {
    const float4* wr = (const float4*)(wih + (size_t)(g * F + j) * F);
    const float4* hr = (const float4*)(whh + (size_t)(g * F + j) * F);
    float si = 0.f, sh = 0.f;
    for (int k = 0; k < F / 4; ++k) {
      float4 a = w0r[k];
      float4 b = wr[k];
      float4 c = hr[k];
      si += a.x * b.x + a.y * b.y + a.z * b.z + a.w * b.w;
      sh += a.x * c.x + a.y * c.y + a.z * c.z + a.w * c.w;
    }
    gi[g] = si + bih[g * F + j];
    gh[g] = sh + bhh[g * F + j];
  }
  float r = 1.0f / (1.0f + expf(-(gi[0] + gh[0])));
  float z = 1.0f / (1.0f + expf(-(gi[1] + gh[1])));
  float nn = tanhf(gi[2] + r * gh[2]);
  float val = (1.0f - z) * nn + z * W0[(size_t)i * F + j];

  // split into hi (truncated) + lo (RNE of residual)
  unsigned u = __float_as_uint(val);
  unsigned short hi = (unsigned short)(u >> 16);
  float lo_f = val - __uint_as_float(u & 0xFFFF0000u);
  unsigned short lo = bf16_rne(lo_f);
  int kstep = i >> 5, kl = i & 31;
  int lane = (kl >> 3) * 16 + (j & 15);
  int tile = j >> 4;
  int idx = ((kstep * 8 + tile) * 64 + lane) * 8 + (kl & 7);
  Bhi[idx] = hi;
  Blo[idx] = lo;
}

// ---------------- CSR build ----------------
__global__ void count_rank_k(const int* __restrict__ dst, int* __restrict__ counts,
                             int* __restrict__ rank, int E) {
  int e = blockIdx.x * blockDim.x + threadIdx.x;
  if (e < E) rank[e] = atomicAdd(&counts[dst[e]], 1);
}

__global__ void scan_local_k(const int* __restrict__ counts, int* __restrict__ incl,
                             int* __restrict__ blocksum, int n) {
  __shared__ int sh[SB];
  int gid = blockIdx.x * SB + threadIdx.x;
  int v = (gid < n) ? counts[gid] : 0;
  sh[threadIdx.x] = v;
  __syncthreads();
  for (int off = 1; off < SB; off <<= 1) {
    int t = 0;
    if ((int)threadIdx.x >= off) t = sh[threadIdx.x - off];
    __syncthreads();
    if ((int)threadIdx.x >= off) sh[threadIdx.x] += t;
    __syncthreads();
  }
  if (gid < n) incl[gid] = sh[threadIdx.x];
  if (threadIdx.x == SB - 1) blocksum[blockIdx.x] = sh[SB - 1];
}

__global__ void scan_blocks_k(int* __restrict__ blocksum, int nb) {
  __shared__ int sh[SB];
  int v = ((int)threadIdx.x < nb) ? blocksum[threadIdx.x] : 0;
  sh[threadIdx.x] = v;
  __syncthreads();
  for (int off = 1; off < SB; off <<= 1) {
    int t = 0;
    if ((int)threadIdx.x >= off) t = sh[threadIdx.x - off];
    __syncthreads();
    if ((int)threadIdx.x >= off) sh[threadIdx.x] += t;
    __syncthreads();
  }
  if ((int)threadIdx.x < nb) blocksum[threadIdx.x] = sh[threadIdx.x] - v;  // exclusive
}

__global__ void scan_finish_k(const int* __restrict__ counts, const int* __restrict__ incl,
                              const int* __restrict__ blocksum, int* __restrict__ rowptr,
                              float* __restrict__ dinv, int n) {
  int gid = blockIdx.x * SB + threadIdx.x;
  if (gid >= n) return;
  int c = counts[gid];
  int inc = blocksum[blockIdx.x] + incl[gid];
  rowptr[gid] = inc - c;
  dinv[gid] = rsqrtf((float)c + 1.0f);
  if (gid == n - 1) rowptr[n] = inc;
}

__global__ void fill_k(const int* __restrict__ src, const int* __restrict__ dst,
                       const int* __restrict__ rank, const int* __restrict__ rowptr,
                       int* __restrict__ csr_src, int E) {
  int e = blockIdx.x * blockDim.x + threadIdx.x;
  if (e < E) {
    int d = dst[e];
    csr_src[rowptr[d] + rank[e]] = src[e];
  }
}

// ---------------- MFMA GEMM: Y' = bf16(dinv[row] * (X @ W)) ----------------
// One wave per 16 rows. Split-bf16 (hi+lo): X@W = Xhi@Whi + Xlo@Whi + Xhi@Wlo
// (fp32-grade accuracy). Output written in C-fragment-native tiled layout:
//   uint at g*1024 + tp*256 + r*64 + lane holds bf16x2 of
//   (row 16g+4*(lane>>4)+r, cols {32tp+(lane&15), 32tp+16+(lane&15)}).
__global__ void gemm_mfma_k(const float* __restrict__ X,
                            const unsigned short* __restrict__ Bhi,
                            const unsigned short* __restrict__ Blo,
                            const float* __restrict__ dinv, unsigned* __restrict__ Y,
                            int nrows) {
  int wid = (int)((blockIdx.x * blockDim.x + threadIdx.x) >> 6);
  int lane = threadIdx.x & 63;
  int ng = (nrows + 15) >> 4;
  if (wid >= ng) return;
  int g = __builtin_amdgcn_readfirstlane(wid);
  int q = lane >> 4, m = lane & 15;
  int rowA = g * 16 + m;
  if (rowA >= nrows) rowA = nrows - 1;

  f32x4 acc[8];
#pragma unroll
  for (int t = 0; t < 8; ++t) { acc[t].x = 0.f; acc[t].y = 0.f; acc[t].z = 0.f; acc[t].w = 0.f; }

#pragma unroll
  for (int s = 0; s < 4; ++s) {
    const float* xp = X + (size_t)rowA * F + s * 32 + q * 8;
    float4 xa = *(const float4*)xp;
    float4 xb = *(const float4*)(xp + 4);
    float xv[8] = {xa.x, xa.y, xa.z, xa.w, xb.x, xb.y, xb.z, xb.w};
    bf16x8 ahi, alo;
#pragma unroll
    for (int j = 0; j < 8; ++j) {
      unsigned u = __float_as_uint(xv[j]);
      ahi[j] = (short)(u >> 16);
      float lf = xv[j] - __uint_as_float(u & 0xFFFF0000u);
      alo[j] = (short)bf16_rne(lf);
    }
#pragma unroll
    for (int t = 0; t < 8; ++t) {
      size_t boff = ((size_t)(s * 8 + t) * 64 + lane) * 8;
      bf16x8 bh = *(const bf16x8*)(Bhi + boff);
      bf16x8 bl = *(const bf16x8*)(Blo + boff);
      acc[t] = __builtin_amdgcn_mfma_f32_16x16x32_bf16(ahi, bh, acc[t], 0, 0, 0);
      acc[t] = __builtin_amdgcn_mfma_f32_16x16x32_bf16(alo, bh, acc[t], 0, 0, 0);
      acc[t] = __builtin_amdgcn_mfma_f32_16x16x32_bf16(ahi, bl, acc[t], 0, 0, 0);
    }
  }

  // epilogue: scale by dinv[row], pack col pairs (c, c+16), tiled store
  int rbase = g * 16 + q * 4;
  float ddv[4];
  if (rbase + 3 < nrows) {
    float4 d4 = *(const float4*)(dinv + rbase);
    ddv[0] = d4.x; ddv[1] = d4.y; ddv[2] = d4.z; ddv[3] = d4.w;
  } else {
#pragma unroll
    for (int r = 0; r < 4; ++r) ddv[r] = (rbase + r < nrows) ? dinv[rbase + r] : 0.f;
  }
  unsigned* yg = Y + (size_t)g * 1024 + lane;
#pragma unroll
  for (int tp = 0; tp < 4; ++tp) {
#pragma unroll
    for (int r = 0; r < 4; ++r) {
      if (rbase + r < nrows) {
        unsigned u = pack_bf16x2(ddv[r] * acc[2 * tp][r], ddv[r] * acc[2 * tp + 1][r]);
        yg[tp * 256 + r * 64] = u;
      }
    }
  }
}

// ---------------- gather aggregation (+ optional fused logits/log_softmax) ----------------
// xwp is in the tiled layout above. Lane L owns cols c0 = 32*(L>>4)+(L&15), c1 = c0+16.
template <bool FUSE_LOGITS>
__global__ void agg_bf16_k(const int* __restrict__ rowptr, const int* __restrict__ csr_src,
                           const float* __restrict__ dinv, const unsigned* __restrict__ xwp,
                           float* __restrict__ hout,
                           const float* __restrict__ lw, const float* __restrict__ lb,
                           float* __restrict__ outp, int n) {
  int wave = (int)((blockIdx.x * blockDim.x + threadIdx.x) >> 6);
  int lane = threadIdx.x & 63;
  if (wave >= n) return;
  int node = __builtin_amdgcn_readfirstlane(wave);
  int lp = ((lane >> 4) << 8) + (lane & 15);   // lane part of tiled offset
  float dd = dinv[node];
  unsigned um = xwp[row_off(node) + lp];
  float accx = unpk_lo(um), accy = unpk_hi(um);
  int b = rowptr[node], e = rowptr[node + 1];
  int i = b;
  for (; i + 8 <= e; i += 8) {
    int s0 = csr_src[i + 0], s1 = csr_src[i + 1], s2 = csr_src[i + 2], s3 = csr_src[i + 3];
    int s4 = csr_src[i + 4], s5 = csr_src[i + 5], s6 = csr_src[i + 6], s7 = csr_src[i + 7];
    unsigned u0 = xwp[row_off(s0) + lp];
    unsigned u1 = xwp[row_off(s1) + lp];
    unsigned u2 = xwp[row_off(s2) + lp];
    unsigned u3 = xwp[row_off(s3) + lp];
    unsigned u4 = xwp[row_off(s4) + lp];
    unsigned u5 = xwp[row_off(s5) + lp];
    unsigned u6 = xwp[row_off(s6) + lp];
    unsigned u7 = xwp[row_off(s7) + lp];
    accx += unpk_lo(u0); accy += unpk_hi(u0);
    accx += unpk_lo(u1); accy += unpk_hi(u1);
    accx += unpk_lo(u2); accy += unpk_hi(u2);
    accx += unpk_lo(u3); accy += unpk_hi(u3);
    accx += unpk_lo(u4); accy += unpk_hi(u4);
    accx += unpk_lo(u5); accy += unpk_hi(u5);
    accx += unpk_lo(u6); accy += unpk_hi(u6);
    accx += unpk_lo(u7); accy += unpk_hi(u7);
  }
  for (; i < e; ++i) {
    int s = csr_src[i];
    unsigned u = xwp[row_off(s) + lp];
    accx += unpk_lo(u); accy += unpk_hi(u);
  }
  float hx = fmaxf(dd * accx, 0.f);
  float hy = fmaxf(dd * accy, 0.f);
  int c0 = ((lane >> 4) << 5) + (lane & 15);   // 32*(lane>>4) + m
  int c1 = c0 + 16;
  if (!FUSE_LOGITS) {
    hout[(size_t)node * F + c0] = hx;
    hout[(size_t)node * F + c1] = hy;
  } else {
    float acc[C_OUT];
#pragma unroll
    for (int c = 0; c < C_OUT; ++c) {
      float v = hx * lw[(size_t)c * F + c0] + hy * lw[(size_t)c * F + c1];
#pragma unroll
      for (int off = 1; off < 64; off <<= 1) v += __shfl_xor(v, off);
      acc[c] = v + lb[c];
    }
    float mx = acc[0];
#pragma unroll
    for (int c = 1; c < C_OUT; ++c) mx = fmaxf(mx, acc[c]);
    float s = 0.f;
#pragma unroll
    for (int c = 0; c < C_OUT; ++c) s += expf(acc[c] - mx);
    float lse = mx + logf(s);
#pragma unroll
    for (int c = 0; c < C_OUT; ++c)
      if (lane == c) outp[(size_t)node * C_OUT + c] = acc[c] - lse;
  }
}

extern "C" void kernel_launch(void* const* d_in, const int* in_sizes, int n_in,
                              void* d_out, int out_size, void* d_ws, size_t ws_size,
                              hipStream_t stream) {
  const float* x    = (const float*)d_in[0];
  const int*   ei   = (const int*)d_in[1];
  const float* W1   = (const float*)d_in[2];
  const float* wih1 = (const float*)d_in[3];
  const float* whh1 = (const float*)d_in[4];
  const float* bih1 = (const float*)d_in[5];
  const float* bhh1 = (const float*)d_in[6];
  const float* W2   = (const float*)d_in[7];
  const float* wih2 = (const float*)d_in[8];
  const float* whh2 = (const float*)d_in[9];
  const float* bih2 = (const float*)d_in[10];
  const float* bhh2 = (const float*)d_in[11];
  const float* lw   = (const float*)d_in[12];
  const float* lb   = (const float*)d_in[13];
  float* out = (float*)d_out;

  int N = in_sizes[0] / F;
  int E = in_sizes[1] / 2;
  const int* src = ei;
  const int* dst = ei + E;
  int nb = (N + SB - 1) / SB;   // 196 for N=50000 (must be <= 256)
  int ng = (N + 15) / 16;       // 16-row groups

  float* ws   = (float*)d_ws;
  unsigned* bufA = (unsigned*)ws;          // N*64 uints (tiled bf16x2 xw')
  float* bufB = ws + (size_t)N * F / 2;    // N*F floats (h)
  float* dinv = bufB + (size_t)N * F;      // N
  unsigned short* Bhi1 = (unsigned short*)(dinv + N);  // 16384 each
  unsigned short* Blo1 = Bhi1 + F * F;
  unsigned short* Bhi2 = Blo1 + F * F;
  unsigned short* Blo2 = Bhi2 + F * F;
  int* counts = (int*)(Blo2 + F * F);      // N
  int* rowptr = counts + N;                // N+1
  int* rank   = rowptr + N + 1;            // E
  int* incl   = rank + E;                  // N
  int* blocksum = incl + N;                // nb (<=256)
  int* csr_src = blocksum + 256;           // E

  // evolve weights (both layers, packed bf16 hi/lo B-fragments) + zero counts
  gru_evolve2_k<<<128 + nb, 256, 0, stream>>>(W1, wih1, whh1, bih1, bhh1,
                                              W2, wih2, whh2, bih2, bhh2,
                                              Bhi1, Blo1, Bhi2, Blo2, counts, N);

  // ----- CSR build + normalization (parallel scan) -----
  count_rank_k<<<(E + 255) / 256, 256, 0, stream>>>(dst, counts, rank, E);
  scan_local_k<<<nb, SB, 0, stream>>>(counts, incl, blocksum, N);
  scan_blocks_k<<<1, SB, 0, stream>>>(blocksum, nb);
  scan_finish_k<<<nb, SB, 0, stream>>>(counts, incl, blocksum, rowptr, dinv, N);
  fill_k<<<(E + 255) / 256, 256, 0, stream>>>(src, dst, rank, rowptr, csr_src, E);

  // ----- layer 1 -----
  gemm_mfma_k<<<(ng + 3) / 4, 256, 0, stream>>>(x, Bhi1, Blo1, dinv, bufA, N);
  agg_bf16_k<false><<<(N + 3) / 4, 256, 0, stream>>>(rowptr, csr_src, dinv, bufA, bufB,
                                                     nullptr, nullptr, nullptr, N);

  // ----- layer 2 (logits fused) -----
  gemm_mfma_k<<<(ng + 3) / 4, 256, 0, stream>>>(bufB, Bhi2, Blo2, dinv, bufA, N);
  agg_bf16_k<true><<<(N + 3) / 4, 256, 0, stream>>>(rowptr, csr_src, dinv, bufA, nullptr,
                                                    lw, lb, out, N);
}

// Round 8
// 289.158 us; speedup vs baseline: 10.3580x; 1.0781x over previous
//
#include <hip/hip_runtime.h>
#include <cstddef>
#include <cstdint>

#define F 128
#define C_OUT 10
#define SB 256   // scan block size

typedef short bf16x8 __attribute__((ext_vector_type(8)));
typedef float f32x4  __attribute__((ext_vector_type(4)));

// ---- bf16 pack helpers ----
__device__ __forceinline__ unsigned pack_bf16x2(float a, float b) {
  unsigned ua = __float_as_uint(a);
  unsigned ub = __float_as_uint(b);
  ua = (ua + 0x7FFFu + ((ua >> 16) & 1u)) >> 16;
  ub = (ub + 0x7FFFu + ((ub >> 16) & 1u)) >> 16;
  return ua | (ub << 16);
}
__device__ __forceinline__ float unpk_lo(unsigned p) { return __uint_as_float(p << 16); }
__device__ __forceinline__ float unpk_hi(unsigned p) { return __uint_as_float(p & 0xFFFF0000u); }
__device__ __forceinline__ unsigned short bf16_rne(float f) {
  unsigned u = __float_as_uint(f);
  return (unsigned short)((u + 0x7FFFu + ((u >> 16) & 1u)) >> 16);
}

// ---------------- GRU weight evolution (both layers) + zero counts ----------------
// Packs W' (split bf16 hi/lo) in MFMA fragment order; used as the A operand
// (A[m][k], m = w_col & 15, k = quad*8 + j), tile = w_col >> 4, kstep = k >> 5:
//   idx = ((kstep*8 + tile)*64 + quad*16 + (w_col&15))*8 + (k&7)
// blocks [0,128): gru ; blocks [128, 128+nbz): zero counts
__global__ void gru_evolve2_k(const float* __restrict__ W01, const float* __restrict__ wih1,
                              const float* __restrict__ whh1, const float* __restrict__ bih1,
                              const float* __restrict__ bhh1,
                              const float* __restrict__ W02, const float* __restrict__ wih2,
                              const float* __restrict__ whh2, const float* __restrict__ bih2,
                              const float* __restrict__ bhh2,
                              unsigned short* __restrict__ Bhi1, unsigned short* __restrict__ Blo1,
                              unsigned short* __restrict__ Bhi2, unsigned short* __restrict__ Blo2,
                              int* __restrict__ counts, int n) {
  if ((int)blockIdx.x >= 128) {
    int i = ((int)blockIdx.x - 128) * SB + threadIdx.x;
    if (i < n) counts[i] = 0;
    return;
  }
  int t = blockIdx.x * 256 + threadIdx.x;     // 0..32767
  int layer = t >> 14;
  int tt = t & 16383;
  const float* W0  = layer ? W02  : W01;
  const float* wih = layer ? wih2 : wih1;
  const float* whh = layer ? whh2 : whh1;
  const float* bih = layer ? bih2 : bih1;
  const float* bhh = layer ? bhh2 : bhh1;
  unsigned short* Bhi = layer ? Bhi2 : Bhi1;
  unsigned short* Blo = layer ? Blo2 : Blo1;
  int i = tt >> 7, j = tt & 127;      // i = k (feature) index, j = w_col index
  const float4* w0r = (const float4*)(W0 + (size_t)i * F);
  float gi[3], gh[3];
#pragma unroll
  for (int g = 0; g < 3; ++g) {
    const float4* wr = (const float4*)(wih + (size_t)(g * F + j) * F);
    const float4* hr = (const float4*)(whh + (size_t)(g * F + j) * F);
    float si = 0.f, sh = 0.f;
    for (int k = 0; k < F / 4; ++k) {
      float4 a = w0r[k];
      float4 b = wr[k];
      float4 c = hr[k];
      si += a.x * b.x + a.y * b.y + a.z * b.z + a.w * b.w;
      sh += a.x * c.x + a.y * c.y + a.z * c.z + a.w * c.w;
    }
    gi[g] = si + bih[g * F + j];
    gh[g] = sh + bhh[g * F + j];
  }
  float r = 1.0f / (1.0f + expf(-(gi[0] + gh[0])));
  float z = 1.0f / (1.0f + expf(-(gi[1] + gh[1])));
  float nn = tanhf(gi[2] + r * gh[2]);
  float val = (1.0f - z) * nn + z * W0[(size_t)i * F + j];

  // split into hi (truncated) + lo (RNE of residual)
  unsigned u = __float_as_uint(val);
  unsigned short hi = (unsigned short)(u >> 16);
  float lo_f = val - __uint_as_float(u & 0xFFFF0000u);
  unsigned short lo = bf16_rne(lo_f);
  int kstep = i >> 5, kl = i & 31;
  int lane = (kl >> 3) * 16 + (j & 15);
  int tile = j >> 4;
  int idx = ((kstep * 8 + tile) * 64 + lane) * 8 + (kl & 7);
  Bhi[idx] = hi;
  Blo[idx] = lo;
}

// ---------------- CSR build ----------------
__global__ void count_rank_k(const int* __restrict__ dst, int* __restrict__ counts,
                             int* __restrict__ rank, int E) {
  int e = blockIdx.x * blockDim.x + threadIdx.x;
  if (e < E) rank[e] = atomicAdd(&counts[dst[e]], 1);
}

__global__ void scan_local_k(const int* __restrict__ counts, int* __restrict__ incl,
                             int* __restrict__ blocksum, int n) {
  __shared__ int sh[SB];
  int gid = blockIdx.x * SB + threadIdx.x;
  int v = (gid < n) ? counts[gid] : 0;
  sh[threadIdx.x] = v;
  __syncthreads();
  for (int off = 1; off < SB; off <<= 1) {
    int t = 0;
    if ((int)threadIdx.x >= off) t = sh[threadIdx.x - off];
    __syncthreads();
    if ((int)threadIdx.x >= off) sh[threadIdx.x] += t;
    __syncthreads();
  }
  if (gid < n) incl[gid] = sh[threadIdx.x];
  if (threadIdx.x == SB - 1) blocksum[blockIdx.x] = sh[SB - 1];
}

__global__ void scan_blocks_k(int* __restrict__ blocksum, int nb) {
  __shared__ int sh[SB];
  int v = ((int)threadIdx.x < nb) ? blocksum[threadIdx.x] : 0;
  sh[threadIdx.x] = v;
  __syncthreads();
  for (int off = 1; off < SB; off <<= 1) {
    int t = 0;
    if ((int)threadIdx.x >= off) t = sh[threadIdx.x - off];
    __syncthreads();
    if ((int)threadIdx.x >= off) sh[threadIdx.x] += t;
    __syncthreads();
  }
  if ((int)threadIdx.x < nb) blocksum[threadIdx.x] = sh[threadIdx.x] - v;  // exclusive
}

__global__ void scan_finish_k(const int* __restrict__ counts, const int* __restrict__ incl,
                              const int* __restrict__ blocksum, int* __restrict__ rowptr,
                              float* __restrict__ dinv, int n) {
  int gid = blockIdx.x * SB + threadIdx.x;
  if (gid >= n) return;
  int c = counts[gid];
  int inc = blocksum[blockIdx.x] + incl[gid];
  rowptr[gid] = inc - c;
  dinv[gid] = rsqrtf((float)c + 1.0f);
  if (gid == n - 1) rowptr[n] = inc;
}

__global__ void fill_k(const int* __restrict__ src, const int* __restrict__ dst,
                       const int* __restrict__ rank, const int* __restrict__ rowptr,
                       int* __restrict__ csr_src, int E) {
  int e = blockIdx.x * blockDim.x + threadIdx.x;
  if (e < E) {
    int d = dst[e];
    csr_src[rowptr[d] + rank[e]] = src[e];
  }
}

// ---------------- MFMA GEMM: Y' = bf16(dinv[row] * (X @ W)), LINEAR layout ----------------
// Transposed MFMA: D = W' (A operand) x X^T (B operand) -> D[w_col][x_row].
// Lane holds x_row = lane&15 and 4 consecutive w_cols per tile -> epilogue packs
// linear col pairs {2j,2j+1} directly, no LDS, output row-major (row*64 uints).
// Split-bf16: X@W = Xhi@Whi + Xlo@Whi + Xhi@Wlo (fp32-grade accuracy).
__global__ void gemm_mfma_k(const float* __restrict__ X,
                            const unsigned short* __restrict__ Bhi,
                            const unsigned short* __restrict__ Blo,
                            const float* __restrict__ dinv, unsigned* __restrict__ Y,
                            int nrows) {
  int wid = (int)((blockIdx.x * blockDim.x + threadIdx.x) >> 6);
  int lane = threadIdx.x & 63;
  int ng = (nrows + 15) >> 4;
  if (wid >= ng) return;
  int g = __builtin_amdgcn_readfirstlane(wid);
  int q = lane >> 4, m = lane & 15;
  int rowA = g * 16 + m;                 // x_row this lane loads & owns in C
  if (rowA >= nrows) rowA = nrows - 1;

  f32x4 acc[8];
#pragma unroll
  for (int t = 0; t < 8; ++t) { acc[t].x = 0.f; acc[t].y = 0.f; acc[t].z = 0.f; acc[t].w = 0.f; }

#pragma unroll
  for (int s = 0; s < 4; ++s) {
    const float* xp = X + (size_t)rowA * F + s * 32 + q * 8;
    float4 xa = *(const float4*)xp;
    float4 xb = *(const float4*)(xp + 4);
    float xv[8] = {xa.x, xa.y, xa.z, xa.w, xb.x, xb.y, xb.z, xb.w};
    bf16x8 xhi, xlo;
#pragma unroll
    for (int j = 0; j < 8; ++j) {
      unsigned u = __float_as_uint(xv[j]);
      xhi[j] = (short)(u >> 16);
      float lf = xv[j] - __uint_as_float(u & 0xFFFF0000u);
      xlo[j] = (short)bf16_rne(lf);
    }
#pragma unroll
    for (int t = 0; t < 8; ++t) {
      size_t boff = ((size_t)(s * 8 + t) * 64 + lane) * 8;
      bf16x8 wh = *(const bf16x8*)(Bhi + boff);
      bf16x8 wl = *(const bf16x8*)(Blo + boff);
      acc[t] = __builtin_amdgcn_mfma_f32_16x16x32_bf16(wh, xhi, acc[t], 0, 0, 0);
      acc[t] = __builtin_amdgcn_mfma_f32_16x16x32_bf16(wh, xlo, acc[t], 0, 0, 0);
      acc[t] = __builtin_amdgcn_mfma_f32_16x16x32_bf16(wl, xhi, acc[t], 0, 0, 0);
    }
  }

  // epilogue: lane owns x_row = rowA, w_cols {t*16 + q*4 + 0..3} per tile.
  // uint j0 = (t*16 + q*4)/2 = t*8 + q*2 holds cols {2j0, 2j0+1}.
  int row = g * 16 + m;
  if (row < nrows) {
    float dd = dinv[row];
    unsigned* yr = Y + (size_t)row * 64 + q * 2;
#pragma unroll
    for (int t = 0; t < 8; ++t) {
      uint2 o;
      o.x = pack_bf16x2(dd * acc[t].x, dd * acc[t].y);
      o.y = pack_bf16x2(dd * acc[t].z, dd * acc[t].w);
      *(uint2*)(yr + t * 8) = o;
    }
  }
}

// ---------------- gather aggregation (+ optional fused logits/log_softmax) ----------------
// Linear layout: lane owns cols {2*lane, 2*lane+1}; row s = 64 contiguous uints.
template <bool FUSE_LOGITS>
__global__ void agg_bf16_k(const int* __restrict__ rowptr, const int* __restrict__ csr_src,
                           const float* __restrict__ dinv, const unsigned* __restrict__ xwp,
                           float* __restrict__ hout,
                           const float* __restrict__ lw, const float* __restrict__ lb,
                           float* __restrict__ outp, int n) {
  int wave = (int)((blockIdx.x * blockDim.x + threadIdx.x) >> 6);
  int lane = threadIdx.x & 63;
  if (wave >= n) return;
  int node = __builtin_amdgcn_readfirstlane(wave);
  float dd = dinv[node];
  unsigned um = xwp[(size_t)node * 64 + lane];
  float accx = unpk_lo(um), accy = unpk_hi(um);
  int b = rowptr[node], e = rowptr[node + 1];
  int i = b;
  for (; i + 8 <= e; i += 8) {
    int s0 = csr_src[i + 0], s1 = csr_src[i + 1], s2 = csr_src[i + 2], s3 = csr_src[i + 3];
    int s4 = csr_src[i + 4], s5 = csr_src[i + 5], s6 = csr_src[i + 6], s7 = csr_src[i + 7];
    unsigned u0 = xwp[(size_t)s0 * 64 + lane];
    unsigned u1 = xwp[(size_t)s1 * 64 + lane];
    unsigned u2 = xwp[(size_t)s2 * 64 + lane];
    unsigned u3 = xwp[(size_t)s3 * 64 + lane];
    unsigned u4 = xwp[(size_t)s4 * 64 + lane];
    unsigned u5 = xwp[(size_t)s5 * 64 + lane];
    unsigned u6 = xwp[(size_t)s6 * 64 + lane];
    unsigned u7 = xwp[(size_t)s7 * 64 + lane];
    accx += unpk_lo(u0); accy += unpk_hi(u0);
    accx += unpk_lo(u1); accy += unpk_hi(u1);
    accx += unpk_lo(u2); accy += unpk_hi(u2);
    accx += unpk_lo(u3); accy += unpk_hi(u3);
    accx += unpk_lo(u4); accy += unpk_hi(u4);
    accx += unpk_lo(u5); accy += unpk_hi(u5);
    accx += unpk_lo(u6); accy += unpk_hi(u6);
    accx += unpk_lo(u7); accy += unpk_hi(u7);
  }
  for (; i < e; ++i) {
    int s = csr_src[i];
    unsigned u = xwp[(size_t)s * 64 + lane];
    accx += unpk_lo(u); accy += unpk_hi(u);
  }
  float hx = fmaxf(dd * accx, 0.f);
  float hy = fmaxf(dd * accy, 0.f);
  if (!FUSE_LOGITS) {
    float2 r; r.x = hx; r.y = hy;
    ((float2*)hout)[(size_t)node * 64 + lane] = r;
  } else {
    float acc[C_OUT];
    const float2* lw2 = (const float2*)lw;
#pragma unroll
    for (int c = 0; c < C_OUT; ++c) {
      float2 w = lw2[(size_t)c * 64 + lane];
      float v = hx * w.x + hy * w.y;
#pragma unroll
      for (int off = 1; off < 64; off <<= 1) v += __shfl_xor(v, off);
      acc[c] = v + lb[c];
    }
    float mx = acc[0];
#pragma unroll
    for (int c = 1; c < C_OUT; ++c) mx = fmaxf(mx, acc[c]);
    float s = 0.f;
#pragma unroll
    for (int c = 0; c < C_OUT; ++c) s += expf(acc[c] - mx);
    float lse = mx + logf(s);
#pragma unroll
    for (int c = 0; c < C_OUT; ++c)
      if (lane == c) outp[(size_t)node * C_OUT + c] = acc[c] - lse;
  }
}

extern "C" void kernel_launch(void* const* d_in, const int* in_sizes, int n_in,
                              void* d_out, int out_size, void* d_ws, size_t ws_size,
                              hipStream_t stream) {
  const float* x    = (const float*)d_in[0];
  const int*   ei   = (const int*)d_in[1];
  const float* W1   = (const float*)d_in[2];
  const float* wih1 = (const float*)d_in[3];
  const float* whh1 = (const float*)d_in[4];
  const float* bih1 = (const float*)d_in[5];
  const float* bhh1 = (const float*)d_in[6];
  const float* W2   = (const float*)d_in[7];
  const float* wih2 = (const float*)d_in[8];
  const float* whh2 = (const float*)d_in[9];
  const float* bih2 = (const float*)d_in[10];
  const float* bhh2 = (const float*)d_in[11];
  const float* lw   = (const float*)d_in[12];
  const float* lb   = (const float*)d_in[13];
  float* out = (float*)d_out;

  int N = in_sizes[0] / F;
  int E = in_sizes[1] / 2;
  const int* src = ei;
  const int* dst = ei + E;
  int nb = (N + SB - 1) / SB;   // 196 for N=50000 (must be <= 256)
  int ng = (N + 15) / 16;       // 16-row groups

  float* ws   = (float*)d_ws;
  unsigned* bufA = (unsigned*)ws;          // N*64 uints (linear bf16x2 xw')
  float* bufB = ws + (size_t)N * F / 2;    // N*F floats (h)
  float* dinv = bufB + (size_t)N * F;      // N
  unsigned short* Bhi1 = (unsigned short*)(dinv + N);  // 16384 each
  unsigned short* Blo1 = Bhi1 + F * F;
  unsigned short* Bhi2 = Blo1 + F * F;
  unsigned short* Blo2 = Bhi2 + F * F;
  int* counts = (int*)(Blo2 + F * F);      // N
  int* rowptr = counts + N;                // N+1
  int* rank   = rowptr + N + 1;            // E
  int* incl   = rank + E;                  // N
  int* blocksum = incl + N;                // nb (<=256)
  int* csr_src = blocksum + 256;           // E

  // evolve weights (both layers, packed bf16 hi/lo fragments) + zero counts
  gru_evolve2_k<<<128 + nb, 256, 0, stream>>>(W1, wih1, whh1, bih1, bhh1,
                                              W2, wih2, whh2, bih2, bhh2,
                                              Bhi1, Blo1, Bhi2, Blo2, counts, N);

  // ----- CSR build + normalization (parallel scan) -----
  count_rank_k<<<(E + 255) / 256, 256, 0, stream>>>(dst, counts, rank, E);
  scan_local_k<<<nb, SB, 0, stream>>>(counts, incl, blocksum, N);
  scan_blocks_k<<<1, SB, 0, stream>>>(blocksum, nb);
  scan_finish_k<<<nb, SB, 0, stream>>>(counts, incl, blocksum, rowptr, dinv, N);
  fill_k<<<(E + 255) / 256, 256, 0, stream>>>(src, dst, rank, rowptr, csr_src, E);

  // ----- layer 1 -----
  gemm_mfma_k<<<(ng + 3) / 4, 256, 0, stream>>>(x, Bhi1, Blo1, dinv, bufA, N);
  agg_bf16_k<false><<<(N + 3) / 4, 256, 0, stream>>>(rowptr, csr_src, dinv, bufA, bufB,
                                                     nullptr, nullptr, nullptr, N);

  // ----- layer 2 (logits fused) -----
  gemm_mfma_k<<<(ng + 3) / 4, 256, 0, stream>>>(bufB, Bhi2, Blo2, dinv, bufA, N);
  agg_bf16_k<true><<<(N + 3) / 4, 256, 0, stream>>>(rowptr, csr_src, dinv, bufA, nullptr,
                                                    lw, lb, out, N);
}